// Round 15
// baseline (1266.541 us; speedup 1.0000x reference)
//
#include <hip/hip_runtime.h>
#include <math.h>

// ---------------- problem constants ----------------
constexpr int S_    = 4096;
constexpr int NKV   = 2048;
constexpr int NAUX  = 512;
constexpr int NNEW  = 1536;
constexpr int H_    = 2048;
constexpr int NH_   = 16;
constexpr int HD_   = 128;
constexpr int FF_   = 8192;
constexpr int NQ_   = 2048;   // NNEW + NAUX
constexpr int NK_   = 4096;   // NKV + NQ
constexpr int PRUNE = 409;
constexpr float EPSF = 1e-6f;

typedef __attribute__((ext_vector_type(8))) short bf16x8;
typedef __attribute__((ext_vector_type(16))) float f32x16;

__device__ __forceinline__ ushort f2bf(float x) {
  union { float f; unsigned u; } a; a.f = x;
  unsigned r = a.u + 0x7fffu + ((a.u >> 16) & 1u);
  return (ushort)(r >> 16);
}
__device__ __forceinline__ float bf2f(ushort h) {
  union { unsigned u; float f; } a; a.u = ((unsigned)h) << 16;
  return a.f;
}
__device__ __forceinline__ unsigned cvt_pk_bf16(float a, float b) {
  unsigned r;
  asm("v_cvt_pk_bf16_f32 %0, %1, %2" : "=v"(r) : "v"(a), "v"(b));
  return r;
}
__device__ __forceinline__ float bflo(unsigned w) { union { unsigned u; float f; } x; x.u = w << 16; return x.f; }
__device__ __forceinline__ float bfhi(unsigned w) { union { unsigned u; float f; } x; x.u = w & 0xffff0000u; return x.f; }

// async global->LDS, 16B per lane. LDS dest = base + lane*16 (HW); global src per-lane.
__device__ __forceinline__ void gload16(const ushort* g, ushort* l) {
  __builtin_amdgcn_global_load_lds(
      (const __attribute__((address_space(1))) unsigned int*)g,
      (__attribute__((address_space(3))) unsigned int*)l, 16, 0, 0);
}

// tiled bf16-plane layout: [row>>7][k>>5][(k>>3)&3][row&127][k&7]
// each 128x32 tile = 8KB contiguous = the exact LDS staging image (chunk-major).
__device__ __forceinline__ size_t tileoff(int row, int k, int K) {
  return ((size_t)((row >> 7) * (K >> 5) + (k >> 5)) << 12)
       + (size_t)((((k >> 3) & 3) << 10) + ((row & 127) << 3) + (k & 7));
}

// ---------------- index prep ----------------
__global__ __launch_bounds__(256) void prep_build(
    const int* __restrict__ kv_idxs, const int* __restrict__ aux_idxs,
    const int* __restrict__ new_idxs, const int* __restrict__ positions,
    int* hs_idxs, int* q_pos, int* key_tok, int* k_pos,
    int* map_full, int* in_hs, int* aux_bit, int* pruned_bit, int* last_hs)
{
  int t = blockIdx.x * 256 + threadIdx.x;     // grid covers 4096
  if (t < S_) { map_full[t] = 0; in_hs[t] = 0; aux_bit[t] = 0; pruned_bit[t] = 0; }
  if (t < NQ_) {
    int tok = (t < NNEW) ? new_idxs[t] : aux_idxs[t - NNEW];
    hs_idxs[t] = tok;
    q_pos[t] = positions[tok];
  }
  if (t < NK_) {
    int tok;
    if (t < NKV) tok = kv_idxs[t];
    else { int i = t - NKV; tok = (i < NNEW) ? new_idxs[i] : aux_idxs[i - NNEW]; }
    key_tok[t] = tok;
    k_pos[t] = positions[tok];
  }
  if (t < NNEW && new_idxs[t] == S_ - 1) last_hs[0] = t;
}

__global__ __launch_bounds__(256) void prep_scatter(
    const int* __restrict__ hs_idxs, const int* __restrict__ aux_idxs,
    int* map_full, int* in_hs, int* aux_bit)
{
  int t = blockIdx.x * 256 + threadIdx.x;
  if (t < NQ_) { int tok = hs_idxs[t]; map_full[tok] = t; in_hs[tok] = 1; }
  else if (t < NQ_ + NAUX) { aux_bit[aux_idxs[t - NQ_]] = 1; }
}

// Prune semantics of the reference (bug-compatible): see previous session note.
__global__ __launch_bounds__(256) void prune_set(
    const int* __restrict__ kv_idxs, int* __restrict__ pruned_bit)
{
  int t = blockIdx.x * 256 + threadIdx.x;
  if (t < PRUNE - 1) pruned_bit[kv_idxs[t]] = 1;
  if (t == PRUNE - 1) pruned_bit[S_ - 1] = 1;
}

// ---------------- hs = concat(hidden_states, aux_cache[aux_idxs]) ----------------
__global__ __launch_bounds__(256) void build_hs(
    const float* __restrict__ hidden, const float* __restrict__ auxc,
    const int* __restrict__ aux_idxs, float* __restrict__ hs)
{
  int gid = blockIdx.x * 256 + threadIdx.x;   // NQ*H/4 float4
  int c4 = gid & 511;                          // H/4 = 512
  int i  = gid >> 9;
  const float4* src;
  if (i < NNEW) src = (const float4*)hidden + (size_t)i * 512 + c4;
  else          src = (const float4*)auxc + (size_t)aux_idxs[i - NNEW] * 512 + c4;
  ((float4*)hs)[gid] = *src;
}

// ---------------- rmsnorm -> tiled bf16 hi/lo planes ----------------
__global__ __launch_bounds__(256) void rmsnorm_split(
    const float* __restrict__ in, const float* __restrict__ w,
    ushort* __restrict__ oh, ushort* __restrict__ ol)
{
  int row = blockIdx.x, t = threadIdx.x;
  const float4* r4 = (const float4*)(in + (size_t)row * H_);
  const float4* w4 = (const float4*)w;
  float ss = 0.f;
  float4 v0 = r4[t], v1 = r4[t + 256];
  ss += v0.x*v0.x + v0.y*v0.y + v0.z*v0.z + v0.w*v0.w;
  ss += v1.x*v1.x + v1.y*v1.y + v1.z*v1.z + v1.w*v1.w;
  __shared__ float red[256];
  red[t] = ss; __syncthreads();
  for (int s = 128; s > 0; s >>= 1) { if (t < s) red[t] += red[t + s]; __syncthreads(); }
  float inv = rsqrtf(red[0] / (float)H_ + EPSF);
  float4 wv0 = w4[t], wv1 = w4[t + 256];
  float f[8];
  f[0] = v0.x*inv*wv0.x; f[1] = v0.y*inv*wv0.y; f[2] = v0.z*inv*wv0.z; f[3] = v0.w*inv*wv0.w;
  f[4] = v1.x*inv*wv1.x; f[5] = v1.y*inv*wv1.y; f[6] = v1.z*inv*wv1.z; f[7] = v1.w*inv*wv1.w;
  ushort4 h0, l0, h1, l1;
  h0.x = f2bf(f[0]); l0.x = f2bf(f[0] - bf2f(h0.x));
  h0.y = f2bf(f[1]); l0.y = f2bf(f[1] - bf2f(h0.y));
  h0.z = f2bf(f[2]); l0.z = f2bf(f[2] - bf2f(h0.z));
  h0.w = f2bf(f[3]); l0.w = f2bf(f[3] - bf2f(h0.w));
  h1.x = f2bf(f[4]); l1.x = f2bf(f[4] - bf2f(h1.x));
  h1.y = f2bf(f[5]); l1.y = f2bf(f[5] - bf2f(h1.y));
  h1.z = f2bf(f[6]); l1.z = f2bf(f[6] - bf2f(h1.z));
  h1.w = f2bf(f[7]); l1.w = f2bf(f[7] - bf2f(h1.w));
  size_t o0 = tileoff(row, t * 4, H_);
  size_t o1 = tileoff(row, 1024 + t * 4, H_);
  *(ushort4*)(oh + o0) = h0; *(ushort4*)(ol + o0) = l0;
  *(ushort4*)(oh + o1) = h1; *(ushort4*)(ol + o1) = l1;
}

// ---------------- weight transpose + bf16 hi/lo split (tiled output) ----------------
// W[K][.] f32 (row stride ld) -> Th/Tl tiled [N-panel][kstep][chunk][row][8].
// grid = (N/64, K/64).
__global__ __launch_bounds__(256) void wsplit_t(
    const float* __restrict__ Wsrc, ushort* __restrict__ Th, ushort* __restrict__ Tl,
    int K, int N, int ld)
{
  __shared__ float tile[64][65];
  const int bn = blockIdx.x * 64, bk = blockIdx.y * 64;
  const int t = threadIdx.x;
  #pragma unroll
  for (int r = 0; r < 4; ++r) {
    int idx = t + 256 * r;
    int row = idx >> 4, c = (idx & 15) * 4;
    float4 v = *(const float4*)(Wsrc + (size_t)(bk + row) * ld + bn + c);
    tile[row][c] = v.x; tile[row][c+1] = v.y; tile[row][c+2] = v.z; tile[row][c+3] = v.w;
  }
  __syncthreads();
  #pragma unroll
  for (int r = 0; r < 4; ++r) {
    int idx = t + 256 * r;
    int n = bn + (idx >> 4), k = bk + (idx & 15) * 4;
    int kl = k - bk;
    float v0 = tile[kl][n - bn], v1 = tile[kl+1][n - bn], v2 = tile[kl+2][n - bn], v3 = tile[kl+3][n - bn];
    ushort4 h, l;
    h.x = f2bf(v0); l.x = f2bf(v0 - bf2f(h.x));
    h.y = f2bf(v1); l.y = f2bf(v1 - bf2f(h.y));
    h.z = f2bf(v2); l.z = f2bf(v2 - bf2f(h.z));
    h.w = f2bf(v3); l.w = f2bf(v3 - bf2f(h.w));
    size_t off = tileoff(n, k, K);
    *(ushort4*)(Th + off) = h;
    *(ushort4*)(Tl + off) = l;
  }
}

// ---------------- bf16 MFMA GEMM, single-buffer global_load_lds staging ----------------
// (round-11 proven structure)
// A: tiled planes Ah/Al, or f32 Af (split in-flight, chunk-major ds_write).
// B: tiled planes Bh/Bl. C f32 row-major.
// bt: 3 = bf16x3 (ah*bh + ah*bl + al*bh, err ~2^-17)
//     2 = bf16x2 (ah*bh + al*bh = a*bh, err = a*bl ~2^-9 rel) — skips ALL Bl
//         staging/reads/MFMA: 12 gloads + 16 MFMA per k-step instead of 16+24.
// epi: 0 plain, 1 C=X+acc, 2 C=silu(X)*acc, 3 QKV-fused de-concat (N=3*2048).
// split>=2: K divided into `split` chunks across grid; chunk c writes partials
// to C + c*M*N (contiguous slots); epi ignored for partials.
__global__ __launch_bounds__(256) void gemm_mfma(
    const ushort* __restrict__ Ah, const ushort* __restrict__ Al,
    const float* __restrict__ Af,
    const ushort* __restrict__ Bh, const ushort* __restrict__ Bl,
    float* __restrict__ C, const float* __restrict__ X,
    int M, int N, int K, int epi, int split, int bt)
{
  __shared__ __align__(16) ushort sAh[4096];
  __shared__ __align__(16) ushort sAl[4096];
  __shared__ __align__(16) ushort sBh[4096];
  __shared__ __align__(16) ushort sBl[4096];
  int flat = blockIdx.x;
  int kbeg = 0, kend = K;
  float* Cout = C;
  if (split >= 2) {
    int nb = gridDim.x / split;
    int chunk = flat / nb;
    flat -= chunk * nb;
    int kc = K / split;
    kbeg = chunk * kc; kend = kbeg + kc;
    Cout = C + (size_t)chunk * M * N;
  }
  const int MB = M >> 7;
  const int cM = MB >> 3;
  const int xcd = flat & 7, idxr = flat >> 3;
  const int byi = xcd * cM + (idxr % cM);      // A panel: XCD-resident slab
  const int bxi = idxr / cM;                   // B panel: streamed (L3)
  const int bm = byi * 128, bn = bxi * 128;
  const int t = threadIdx.x;
  const int lane = t & 63;
  const int wid = t >> 6;
  const int wr = wid >> 1, wc = wid & 1;
  const int fr = lane & 31;
  const int kg = lane >> 5;
  const int ub0 = wid * 128;
  const int Ksteps = K >> 5;

  f32x16 acc[2][2];
  #pragma unroll
  for (int mi = 0; mi < 2; ++mi)
    #pragma unroll
    for (int ni = 0; ni < 2; ++ni)
      #pragma unroll
      for (int r = 0; r < 16; ++r) acc[mi][ni][r] = 0.f;

  for (int k0 = kbeg; k0 < kend; k0 += 32) {
    const int ks = k0 >> 5;
    const size_t tB = ((size_t)(bxi * Ksteps + ks)) << 12;
    if (Af) {
      // split-stage A f32 -> chunk-major hi/lo images
      #pragma unroll
      for (int r = 0; r < 2; ++r) {
        int u = t + 256 * r;
        int row = u >> 2, ch = u & 3;
        const float* s0 = Af + (size_t)(bm + row) * K + k0 + ch * 8;
        float4 v0 = *(const float4*)s0, v1 = *(const float4*)(s0 + 4);
        float f[8] = {v0.x,v0.y,v0.z,v0.w,v1.x,v1.y,v1.z,v1.w};
        union { ushort u16[8]; uint4 q; } Hh, Ll;
        #pragma unroll
        for (int j = 0; j < 8; ++j) {
          ushort hh = f2bf(f[j]);
          Hh.u16[j] = hh; Ll.u16[j] = f2bf(f[j] - bf2f(hh));
        }
        *(uint4*)&sAh[ch * 1024 + row * 8] = Hh.q;
        *(uint4*)&sAl[ch * 1024 + row * 8] = Ll.q;
      }
    } else {
      const size_t tA = ((size_t)(byi * Ksteps + ks)) << 12;
      const ushort* a0 = Ah + tA;
      const ushort* a1 = Al + tA;
      gload16(a0 + (size_t)(ub0 + lane) * 8,      sAh + ub0 * 8);
      gload16(a0 + (size_t)(ub0 + 64 + lane) * 8, sAh + (ub0 + 64) * 8);
      gload16(a1 + (size_t)(ub0 + lane) * 8,      sAl + ub0 * 8);
      gload16(a1 + (size_t)(ub0 + 64 + lane) * 8, sAl + (ub0 + 64) * 8);
    }
    {
      const ushort* b0 = Bh + tB;
      gload16(b0 + (size_t)(ub0 + lane) * 8,      sBh + ub0 * 8);
      gload16(b0 + (size_t)(ub0 + 64 + lane) * 8, sBh + (ub0 + 64) * 8);
      if (bt == 3) {
        const ushort* b1 = Bl + tB;
        gload16(b1 + (size_t)(ub0 + lane) * 8,      sBl + ub0 * 8);
        gload16(b1 + (size_t)(ub0 + 64 + lane) * 8, sBl + (ub0 + 64) * 8);
      }
    }
    __syncthreads();
    #pragma unroll
    for (int ksl = 0; ksl < 2; ++ksl) {
      const int co = (ksl * 2 + kg) * 1024;
      bf16x8 ah[2], al[2], bh[2];
      #pragma unroll
      for (int mi = 0; mi < 2; ++mi) {
        ah[mi] = *(const bf16x8*)&sAh[co + (wr * 64 + mi * 32 + fr) * 8];
        al[mi] = *(const bf16x8*)&sAl[co + (wr * 64 + mi * 32 + fr) * 8];
        bh[mi] = *(const bf16x8*)&sBh[co + (wc * 64 + mi * 32 + fr) * 8];
      }
      #pragma unroll
      for (int mi = 0; mi < 2; ++mi)
        #pragma unroll
        for (int ni = 0; ni < 2; ++ni) {
          acc[mi][ni] = __builtin_amdgcn_mfma_f32_32x32x16_bf16(ah[mi], bh[ni], acc[mi][ni], 0, 0, 0);
          acc[mi][ni] = __builtin_amdgcn_mfma_f32_32x32x16_bf16(al[mi], bh[ni], acc[mi][ni], 0, 0, 0);
        }
      if (bt == 3) {
        bf16x8 bl[2];
        #pragma unroll
        for (int ni = 0; ni < 2; ++ni)
          bl[ni] = *(const bf16x8*)&sBl[co + (wc * 64 + ni * 32 + fr) * 8];
        #pragma unroll
        for (int mi = 0; mi < 2; ++mi)
          #pragma unroll
          for (int ni = 0; ni < 2; ++ni)
            acc[mi][ni] = __builtin_amdgcn_mfma_f32_32x32x16_bf16(ah[mi], bl[ni], acc[mi][ni], 0, 0, 0);
      }
    }
    __syncthreads();
  }
  #pragma unroll
  for (int mi = 0; mi < 2; ++mi) {
    #pragma unroll
    for (int ni = 0; ni < 2; ++ni) {
      #pragma unroll
      for (int r = 0; r < 16; ++r) {
        int row = bm + wr * 64 + mi * 32 + (r & 3) + 8 * (r >> 2) + 4 * kg;
        int col = bn + wc * 64 + ni * 32 + fr;
        float v = acc[mi][ni][r];
        size_t idx;
        if (epi == 3) {
          int mtx = col >> 11, cc = col & 2047;
          idx = ((size_t)mtx * M + row) * 2048 + cc;
        } else {
          idx = (size_t)row * N + col;
          if (split < 2) {
            if (epi == 1) v += X[idx];
            else if (epi == 2) { float g = X[idx]; v = (g / (1.f + expf(-g))) * v; }
          }
        }
        Cout[idx] = v;
      }
    }
  }
}

// ---------------- o = sum(parts[0..np)) + x (split-K reduce + residual) ----------------
// parts are contiguous NQ*H f32 planes (stride 4M floats).
__global__ __launch_bounds__(256) void reduce_n(
    const float* __restrict__ parts, const float* __restrict__ x,
    float* __restrict__ o, int np)
{
  int g = blockIdx.x * 256 + threadIdx.x;     // NQ*H/4 float4
  float4 vx = ((const float4*)x)[g];
  float4 vo = vx;
  for (int p = 0; p < np; ++p) {
    float4 vp = ((const float4*)(parts + (size_t)p * NQ_ * H_))[g];
    vo.x += vp.x; vo.y += vp.y; vo.z += vp.z; vo.w += vp.w;
  }
  ((float4*)o)[g] = vo;
}

// ---------------- RoPE in-place on q and k ----------------
__global__ __launch_bounds__(256) void rope_k(
    float* __restrict__ qb, float* __restrict__ kb, const int* __restrict__ q_pos)
{
  int gid = blockIdx.x * 256 + threadIdx.x;   // NQ*NH*64
  int d = gid & 63;
  int h = (gid >> 6) & 15;
  int i = gid >> 10;
  int p = q_pos[i];
  double ang = (double)p * exp((double)d * -0.14391156831212787);
  float c = (float)cos(ang), s = (float)sin(ang);
  size_t ia = (size_t)i * H_ + h * HD_ + d;
  size_t ib = ia + 64;
  float qa = qb[ia], qbv = qb[ib];
  qb[ia] = qa * c - qbv * s;
  qb[ib] = qbv * c + qa * s;
  float ka = kb[ia], kbv = kb[ib];
  kb[ia] = ka * c - kbv * s;
  kb[ib] = kbv * c + ka * s;
}

// ---------------- K (hi/lo) + V^T (hi) bf16 planes ----------------
// kh/kl: [NH][NK][HD]; vth: TILE-MAJOR [NH][NK/64][HD][64].  grid = (NK/64, NH)
__global__ __launch_bounds__(256) void fill_kv_planes(
    const float* __restrict__ kcache, const float* __restrict__ vcache,
    const float* __restrict__ kb, const float* __restrict__ vb,
    const int* __restrict__ kv_idxs,
    ushort* __restrict__ kh, ushort* __restrict__ kl,
    ushort* __restrict__ vth)
{
  __shared__ float vt[64][133];
  const int h = blockIdx.y;
  const int kbase = blockIdx.x * 64;
  const int t = threadIdx.x;
  #pragma unroll
  for (int r = 0; r < 8; ++r) {
    int idx = t + 256 * r;                     // 2048 float4
    int key = idx >> 5, d4 = idx & 31;
    int j = kbase + key;
    float4 kv, vv;
    if (j < NKV) {
      int tok = kv_idxs[j];
      size_t src = ((size_t)h * S_ + tok) * 32 + d4;
      kv = ((const float4*)kcache)[src];
      vv = ((const float4*)vcache)[src];
    } else {
      int i = j - NKV;
      size_t src = (size_t)i * 512 + h * 32 + d4;
      kv = ((const float4*)kb)[src];
      vv = ((const float4*)vb)[src];
    }
    ushort4 hh, ll;
    hh.x = f2bf(kv.x); ll.x = f2bf(kv.x - bf2f(hh.x));
    hh.y = f2bf(kv.y); ll.y = f2bf(kv.y - bf2f(hh.y));
    hh.z = f2bf(kv.z); ll.z = f2bf(kv.z - bf2f(hh.z));
    hh.w = f2bf(kv.w); ll.w = f2bf(kv.w - bf2f(hh.w));
    size_t dst = ((size_t)(h * NK_ + j)) * 128 + d4 * 4;
    *(ushort4*)(kh + dst) = hh;
    *(ushort4*)(kl + dst) = ll;
    vt[key][d4 * 4 + 0] = vv.x; vt[key][d4 * 4 + 1] = vv.y;
    vt[key][d4 * 4 + 2] = vv.z; vt[key][d4 * 4 + 3] = vv.w;
  }
  __syncthreads();
  #pragma unroll
  for (int r = 0; r < 8; ++r) {
    int idx = t + 256 * r;                     // 2048 groups of 4 keys
    int d = idx >> 4, kq = (idx & 15) * 4;
    float v0 = vt[kq + 0][d], v1 = vt[kq + 1][d], v2 = vt[kq + 2][d], v3 = vt[kq + 3][d];
    ushort4 hh;
    hh.x = f2bf(v0); hh.y = f2bf(v1); hh.z = f2bf(v2); hh.w = f2bf(v3);
    size_t dst = (((size_t)h * 64 + blockIdx.x) * 128 + d) * 64 + kq;
    *(ushort4*)(vth + dst) = hh;
  }
}

// ---------------- MFMA flash attention (4-way key-split, grid 1024, LPT order) ----------------
// (benched round-11 structure — unchanged)
struct MergeLDS4 { float buf[2][32][132]; float ml[2][2][32]; };

__global__ __launch_bounds__(256, 2) void flash_mfma(
    const float* __restrict__ qb, const ushort* __restrict__ khg,
    const ushort* __restrict__ klg, const ushort* __restrict__ vthg,
    const int* __restrict__ q_pos, const int* __restrict__ k_pos,
    ushort* __restrict__ ctxh, ushort* __restrict__ ctxl)
{
  __shared__ MergeLDS4 U;
  const int b = blockIdx.x;
  const int h = (b & 7) * 2 + ((b >> 3) & 1);  // 2 heads per XCD slab
  const int qb32 = 63 - (b >> 4);              // heaviest blocks first (LPT)
  const int q0 = qb32 * 32;
  const int t = threadIdx.x;
  const int wk = t >> 6, lane = t & 63;
  const int kg = lane >> 5;
  const int qc = lane & 31;
  const int qi = q0 + qc;
  const float scale = 0.08838834764831844f;    // 1/sqrt(128)

  bf16x8 qh[8], ql[8];
  {
    const float4* q4 = (const float4*)qb;
    #pragma unroll
    for (int s = 0; s < 8; ++s) {
      size_t a = (size_t)qi * 512 + h * 32 + s * 4 + kg * 2;
      float4 f0 = q4[a], f1 = q4[a + 1];
      float f[8] = {f0.x, f0.y, f0.z, f0.w, f1.x, f1.y, f1.z, f1.w};
      union { ushort u[8]; bf16x8 v; } Hq, Lq;
      #pragma unroll
      for (int j = 0; j < 8; ++j) {
        float qs = f[j] * scale;
        ushort hh = f2bf(qs);
        Hq.u[j] = hh; Lq.u[j] = f2bf(qs - bf2f(hh));
      }
      qh[s] = Hq.v; ql[s] = Lq.v;
    }
  }
  const int qp = q_pos[qi];
  const int wave_qmin = __shfl(qp, 0);
  const int wave_qmax = __shfl(qp, 31);       // q ascend within 32-block

  const ushort* kh_base = khg + (size_t)h * NK_ * 128;
  const ushort* kl_base = klg + (size_t)h * NK_ * 128;
  const ushort* vt_base = vthg + (size_t)h * NK_ * 128;   // [NK/64][128][64]

  f32x16 acc[4];
  #pragma unroll
  for (int f = 0; f < 4; ++f)
    #pragma unroll
    for (int r = 0; r < 16; ++r) acc[f][r] = 0.f;
  float m_run = -INFINITY, l_run = 0.f;

  for (int c = wk; c < NK_ / 32; c += 4) {     // interleaved 32-key chunks
    const int krow0 = c * 32;
    const int kpv = k_pos[krow0 + qc];
    if (__shfl(kpv, 0) > wave_qmax) continue;  // chunk fully masked
    const bool needmask = (__shfl(kpv, 31) > wave_qmin);

    f32x16 sA, sB;
    #pragma unroll
    for (int r = 0; r < 16; ++r) { sA[r] = 0.f; sB[r] = 0.f; }
    const ushort* krow = kh_base + (size_t)(krow0 + qc) * 128 + kg * 8;
    const ushort* lrow = kl_base + (size_t)(krow0 + qc) * 128 + kg * 8;
    __builtin_amdgcn_s_setprio(1);
    #pragma unroll
    for (int s = 0; s < 8; ++s) {
      bf16x8 khf = *(const bf16x8*)(krow + s * 16);
      bf16x8 klf = *(const bf16x8*)(lrow + s * 16);
      sA = __builtin_amdgcn_mfma_f32_32x32x16_bf16(khf, qh[s], sA, 0, 0, 0);
      sB = __builtin_amdgcn_mfma_f32_32x32x16_bf16(khf, ql[s], sB, 0, 0, 0);
      sB = __builtin_amdgcn_mfma_f32_32x32x16_bf16(klf, qh[s], sB, 0, 0, 0);
    }
    __builtin_amdgcn_s_setprio(0);
    // V fragments from tile-major layout (issued early, hide under softmax)
    bf16x8 vf[2][4];
    {
      const ushort* vtile = vt_base + (size_t)(c >> 1) * 8192;   // 128*64
      #pragma unroll
      for (int ks = 0; ks < 2; ++ks) {
        const int kc = (c & 1) * 32 + ks * 16 + kg * 8;          // within-tile key
        #pragma unroll
        for (int f = 0; f < 4; ++f)
          vf[ks][f] = *(const bf16x8*)(vtile + (f * 32 + qc) * 64 + kc);
      }
    }
    float sc[16];
    #pragma unroll
    for (int r = 0; r < 16; ++r) sc[r] = sA[r] + sB[r];
    if (needmask) {
      #pragma unroll
      for (int r = 0; r < 16; ++r) {
        int crow = (r & 3) + 8 * (r >> 2) + 4 * kg;
        sc[r] = (__shfl(kpv, crow) <= qp) ? sc[r] : -INFINITY;
      }
    }
    float mloc = sc[0];
    #pragma unroll
    for (int r = 1; r < 16; ++r) mloc = fmaxf(mloc, sc[r]);
    mloc = fmaxf(mloc, __shfl_xor(mloc, 32));
    float m_new = fmaxf(m_run, mloc);
    float mexp = (m_new == -INFINITY) ? 0.f : m_new;
    if (__any(m_new > m_run)) {
      float aa = __expf(m_run - mexp);
      l_run *= aa;
      #pragma unroll
      for (int f = 0; f < 4; ++f)
        #pragma unroll
        for (int r = 0; r < 16; ++r) acc[f][r] *= aa;
    }
    m_run = m_new;
    float p[16]; float psum = 0.f;
    #pragma unroll
    for (int r = 0; r < 16; ++r) { p[r] = __expf(sc[r] - mexp); psum += p[r]; }
    psum += __shfl_xor(psum, 32);
    l_run += psum;
    bf16x8 pfh[2], pfl[2];
    #pragma unroll
    for (int sl = 0; sl < 2; ++sl) {
      const float* pp = p + sl * 8;
      unsigned a0 = cvt_pk_bf16(pp[0], pp[1]);
      unsigned a1 = cvt_pk_bf16(pp[2], pp[3]);
      unsigned b0 = cvt_pk_bf16(pp[4], pp[5]);
      unsigned b1 = cvt_pk_bf16(pp[6], pp[7]);
      unsigned a0x = (unsigned)__shfl_xor((int)a0, 32);
      unsigned a1x = (unsigned)__shfl_xor((int)a1, 32);
      unsigned b0x = (unsigned)__shfl_xor((int)b0, 32);
      unsigned b1x = (unsigned)__shfl_xor((int)b1, 32);
      union { unsigned wd[4]; bf16x8 v; } PH, PL;
      PH.wd[0] = kg ? b0x : a0;
      PH.wd[1] = kg ? b1x : a1;
      PH.wd[2] = kg ? b0 : a0x;
      PH.wd[3] = kg ? b1 : a1x;
      float r0 = pp[0] - bflo(a0), r1 = pp[1] - bfhi(a0);
      float r2 = pp[2] - bflo(a1), r3 = pp[3] - bfhi(a1);
      float r4 = pp[4] - bflo(b0), r5 = pp[5] - bfhi(b0);
      float r6 = pp[6] - bflo(b1), r7 = pp[7] - bfhi(b1);
      unsigned c0 = cvt_pk_bf16(r0, r1);
      unsigned c1 = cvt_pk_bf16(r2, r3);
      unsigned d0 = cvt_pk_bf16(r4, r5);
      unsigned d1 = cvt_pk_bf16(r6, r7);
      unsigned c0x = (unsigned)__shfl_xor((int)c0, 32);
      unsigned c1x = (unsigned)__shfl_xor((int)c1, 32);
      unsigned d0x = (unsigned)__shfl_xor((int)d0, 32);
      unsigned d1x = (unsigned)__shfl_xor((int)d1, 32);
      PL.wd[0] = kg ? d0x : c0;
      PL.wd[1] = kg ? d1x : c1;
      PL.wd[2] = kg ? d0 : c0x;
      PL.wd[3] = kg ? d1 : c1x;
      pfh[sl] = PH.v; pfl[sl] = PL.v;
    }
    __builtin_amdgcn_s_setprio(1);
    #pragma unroll
    for (int ks = 0; ks < 2; ++ks) {
      acc[0] = __builtin_amdgcn_mfma_f32_32x32x16_bf16(vf[ks][0], pfh[ks], acc[0], 0, 0, 0);
      acc[1] = __builtin_amdgcn_mfma_f32_32x32x16_bf16(vf[ks][1], pfh[ks], acc[1], 0, 0, 0);
      acc[2] = __builtin_amdgcn_mfma_f32_32x32x16_bf16(vf[ks][2], pfh[ks], acc[2], 0, 0, 0);
      acc[3] = __builtin_amdgcn_mfma_f32_32x32x16_bf16(vf[ks][3], pfh[ks], acc[3], 0, 0, 0);
      acc[0] = __builtin_amdgcn_mfma_f32_32x32x16_bf16(vf[ks][0], pfl[ks], acc[0], 0, 0, 0);
      acc[1] = __builtin_amdgcn_mfma_f32_32x32x16_bf16(vf[ks][1], pfl[ks], acc[1], 0, 0, 0);
      acc[2] = __builtin_amdgcn_mfma_f32_32x32x16_bf16(vf[ks][2], pfl[ks], acc[2], 0, 0, 0);
      acc[3] = __builtin_amdgcn_mfma_f32_32x32x16_bf16(vf[ks][3], pfl[ks], acc[3], 0, 0, 0);
    }
    __builtin_amdgcn_s_setprio(0);
  }

  // ---- 2-stage 4-way merge (guarded online-softmax combine) ----
  if (wk >= 2) {
    const int slot = wk - 2;
    #pragma unroll
    for (int f = 0; f < 4; ++f)
      #pragma unroll
      for (int r = 0; r < 16; ++r) {
        int d = f * 32 + (r & 3) + 8 * (r >> 2) + 4 * kg;
        U.buf[slot][qc][d] = acc[f][r];
      }
    if (kg == 0) { U.ml[slot][0][qc] = m_run; U.ml[slot][1][qc] = l_run; }
  }
  __syncthreads();
  if (wk < 2) {
    const int slot = wk;
    float m2 = U.ml[slot][0][qc];
    float l2 = U.ml[slot][1][qc];
    float mm = fmaxf(m_run, m2);
    float me = (mm == -INFINITY) ? 0.f : mm;
    float a1 = __expf(m_run - me);
    float a2 = __expf(m2 - me);
    #pragma unroll
    for (int f = 0; f < 4; ++f)
      #pragma unroll
      for (int r = 0; r < 16; ++r) {
        int d = f * 32 + (r & 3) + 8 * (r >> 2) + 4 * kg;
        acc[f][r] = acc[f][r] * a1 + U.buf[slot][qc][d] * a2;
      }
    m_run = mm; l_run = l_run * a1 + l2 * a2;
  }
  __syncthreads();
  if (wk == 1) {
    #pragma unroll
    for (int f = 0; f < 4; ++f)
      #pragma unroll
      for (int r = 0; r < 16; ++r) {
        int d = f * 32 + (r & 3) + 8 * (r >> 2) + 4 * kg;
        U.buf[0][qc][d] = acc[f][r];
      }
    if (kg == 0) { U.ml[0][0][qc] = m_run; U.ml[0][1][qc] = l_run; }
  }
  __syncthreads();
  if (wk == 0) {
    float m2 = U.ml[0][0][qc];
    float l2 = U.ml[0][1][qc];
    float mm = fmaxf(m_run, m2);
    float me = (mm == -INFINITY) ? 0.f : mm;
    float a1 = __expf(m_run - me);
    float a2 = __expf(m2 - me);
    float lt = l_run * a1 + l2 * a2;
    float inv = 1.f / lt;
    #pragma unroll
    for (int f = 0; f < 4; ++f)
      #pragma unroll
      for (int rq = 0; rq < 4; ++rq) {
        float o[4];
        #pragma unroll
        for (int j = 0; j < 4; ++j) {
          int d = f * 32 + j + 8 * rq + 4 * kg;
          o[j] = (acc[f][rq * 4 + j] * a1 + U.buf[0][qc][d] * a2) * inv;
        }
        ushort4 hh, ll;
        hh.x = f2bf(o[0]); ll.x = f2bf(o[0] - bf2f(hh.x));
        hh.y = f2bf(o[1]); ll.y = f2bf(o[1] - bf2f(hh.y));
        hh.z = f2bf(o[2]); ll.z = f2bf(o[2] - bf2f(hh.z));
        hh.w = f2bf(o[3]); ll.w = f2bf(o[3] - bf2f(hh.w));
        int d = h * 128 + f * 32 + kg * 4 + rq * 8;
        size_t oidx = tileoff(qi, d, H_);
        *(ushort4*)(ctxh + oidx) = hh;
        *(ushort4*)(ctxl + oidx) = ll;
      }
  }
}

// ---------------- cache scatter outputs ----------------
__global__ __launch_bounds__(256) void write_kv(
    const float* __restrict__ kcache, const float* __restrict__ vcache,
    const float* __restrict__ kb, const float* __restrict__ vb,
    const int* __restrict__ in_hs, const int* __restrict__ map_full,
    float* __restrict__ kc_o, float* __restrict__ vc_o)
{
  int gid = blockIdx.x * 256 + threadIdx.x;   // NH*S*HD/4
  int d4 = gid & 31;
  int s  = (gid >> 5) & (S_ - 1);
  int h  = gid >> 17;
  float4 kv, vv;
  if (in_hs[s]) {
    int i = map_full[s];
    size_t src = (size_t)i * (H_ / 4) + h * 32 + d4;
    kv = ((const float4*)kb)[src];
    vv = ((const float4*)vb)[src];
  } else {
    kv = ((const float4*)kcache)[gid];
    vv = ((const float4*)vcache)[gid];
  }
  ((float4*)kc_o)[gid] = kv;
  ((float4*)vc_o)[gid] = vv;
}

__global__ __launch_bounds__(256) void aux_write(
    const float* __restrict__ outb, const float* __restrict__ auxc,
    const int* __restrict__ pruned_bit, const int* __restrict__ aux_bit,
    const int* __restrict__ map_full, float* __restrict__ aux_o)
{
  int gid = blockIdx.x * 256 + threadIdx.x;   // S*H/4
  int c4 = gid & 511;
  int s  = gid >> 9;
  float4 v;
  if (pruned_bit[s] && !aux_bit[s])
    v = ((const float4*)outb)[(size_t)map_full[s] * 512 + c4];
  else
    v = ((const float4*)auxc)[gid];
  ((float4*)aux_o)[gid] = v;
}

// ---------------- host ----------------
extern "C" void kernel_launch(void* const* d_in, const int* in_sizes, int n_in,
                              void* d_out, int out_size, void* d_ws, size_t ws_size,
                              hipStream_t stream) {
  (void)in_sizes; (void)n_in; (void)out_size; (void)ws_size;
  const float* hidden  = (const float*)d_in[0];
  const float* kcache  = (const float*)d_in[1];
  const float* vcache  = (const float*)d_in[2];
  const float* auxc    = (const float*)d_in[3];
  const int* kv_idxs   = (const int*)d_in[4];
  const int* aux_idxs  = (const int*)d_in[5];
  const int* new_idxs  = (const int*)d_in[6];
  const int* positions = (const int*)d_in[7];
  const float* wq      = (const float*)d_in[8];
  const float* wk      = (const float*)d_in[9];
  const float* wv      = (const float*)d_in[10];
  const float* wo      = (const float*)d_in[11];
  const float* w_gate  = (const float*)d_in[12];
  const float* w_up    = (const float*)d_in[13];
  const float* w_down  = (const float*)d_in[14];
  const float* ln1     = (const float*)d_in[15];
  const float* ln2     = (const float*)d_in[16];

  float* out_o = (float*)d_out;
  float* kc_o  = out_o + (size_t)NQ_ * H_;
  float* vc_o  = kc_o + (size_t)NH_ * S_ * HD_;
  float* aux_o = vc_o + (size_t)NH_ * S_ * HD_;

  // workspace (units of M4 = 4M floats = 16.78 MB), 11 slots + ints.
  // wo split-K=4: partials -> slots 2,3,4,5 (qb/kb/vb/khp dead after flash/write_kv)
  // down split-K=2: partials -> slots 0,1 (hs, x-planes dead by then)
  float* W = (float*)d_ws;
  const size_t M4 = 4194304;                  // NQ*H
  float* hs    = W;
  ushort* xh   = (ushort*)(W + 1 * M4);
  ushort* xl   = xh + (size_t)NQ_ * H_;
  float* qb    = W + 2 * M4;
  float* kb    = W + 3 * M4;
  float* vb    = W + 4 * M4;
  ushort* bt3_h = (ushort*)(W + 5 * M4);      // 3*H*H ushorts (slots 5-6, QKV phase)
  ushort* bt3_l = (ushort*)(W + 8 * M4);      // slots 8-9 (QKV phase only)
  ushort* khp  = (ushort*)(W + 5 * M4);
  ushort* klp  = (ushort*)(W + 6 * M4);
  ushort* vthp = (ushort*)(W + 7 * M4);
  ushort* ctxh = (ushort*)(W + 8 * M4);
  ushort* ctxl = ctxh + (size_t)NQ_ * H_;
  ushort* bt_h = (ushort*)(W + 9 * M4);
  ushort* bt_l = bt_h + (size_t)H_ * H_;
  float* hs2   = W + 10 * M4;
  float* act   = W + 2 * M4;                  // slots 2-5 (FFN phase)
  ushort* btg_h = (ushort*)(W + 6 * M4);      // slots 6-7
  ushort* btg_l = (ushort*)(W + 8 * M4);      // slots 8-9
  float* wo_p  = W + 2 * M4;                  // wo split-4 partials (slots 2-5)
  float* dn_p  = W + 0 * M4;                  // down split-2 partials (slots 0-1)
  int* ip = (int*)(W + 11 * M4);
  int* hs_idxs = ip;           ip += NQ_;
  int* q_pos   = ip;           ip += NQ_;
  int* key_tok = ip;           ip += NK_;
  int* k_pos   = ip;           ip += NK_;
  int* map_full= ip;           ip += S_;
  int* in_hs   = ip;           ip += S_;
  int* aux_bit = ip;           ip += S_;
  int* pruned  = ip;           ip += S_;
  int* last_hs = ip;           ip += 4;

  prep_build<<<16, 256, 0, stream>>>(kv_idxs, aux_idxs, new_idxs, positions,
      hs_idxs, q_pos, key_tok, k_pos, map_full, in_hs, aux_bit, pruned, last_hs);
  prep_scatter<<<10, 256, 0, stream>>>(hs_idxs, aux_idxs, map_full, in_hs, aux_bit);
  prune_set<<<2, 256, 0, stream>>>(kv_idxs, pruned);
  build_hs<<<4096, 256, 0, stream>>>(hidden, auxc, aux_idxs, hs);
  rmsnorm_split<<<NQ_, 256, 0, stream>>>(hs, ln1, xh, xl);

  const dim3 gTH(H_ / 64, H_ / 64);
  // QKV fused: B = concat(wq,wk,wv) panels, N = 6144, epi 3 de-concats C. (bf16x3)
  wsplit_t<<<gTH, 256, 0, stream>>>(wq, bt3_h,                      bt3_l,                      H_, H_, H_);
  wsplit_t<<<gTH, 256, 0, stream>>>(wk, bt3_h + (size_t)H_ * H_,    bt3_l + (size_t)H_ * H_,    H_, H_, H_);
  wsplit_t<<<gTH, 256, 0, stream>>>(wv, bt3_h + (size_t)2 * H_ * H_, bt3_l + (size_t)2 * H_ * H_, H_, H_, H_);
  gemm_mfma<<<768, 256, 0, stream>>>(xh, xl, nullptr, bt3_h, bt3_l, qb, nullptr, NQ_, 3 * H_, H_, 3, 0, 3);

  rope_k<<<8192, 256, 0, stream>>>(qb, kb, q_pos);
  fill_kv_planes<<<dim3(64, 16), 256, 0, stream>>>(kcache, vcache, kb, vb, kv_idxs,
      khp, klp, vthp);

  flash_mfma<<<1024, 256, 0, stream>>>(qb, khp, klp, vthp, q_pos, k_pos, ctxh, ctxl);
  write_kv<<<8192, 256, 0, stream>>>(kcache, vcache, kb, vb, in_hs, map_full, kc_o, vc_o);

  // wo GEMM: split-K=4 (grid 1024), bf16x3, partials in slots 2-5, residual-add
  wsplit_t<<<gTH, 256, 0, stream>>>(wo, bt_h, bt_l, H_, H_, H_);
  gemm_mfma<<<1024, 256, 0, stream>>>(ctxh, ctxl, nullptr, bt_h, bt_l, wo_p, nullptr, NQ_, H_, H_, 0, 4, 3);
  reduce_n<<<4096, 256, 0, stream>>>(wo_p, hs, hs2, 4);
  rmsnorm_split<<<NQ_, 256, 0, stream>>>(hs2, ln2, xh, xl);

  // FFN GEMMs: bf16x2 (B-hi only; err ~2^-9 rel, attenuated through down proj)
  wsplit_t<<<dim3(FF_ / 64, H_ / 64), 256, 0, stream>>>(w_gate, btg_h, btg_l, H_, FF_, FF_);
  gemm_mfma<<<1024, 256, 0, stream>>>(xh, xl, nullptr, btg_h, btg_l, act, nullptr, NQ_, FF_, H_, 0, 0, 2);
  wsplit_t<<<dim3(FF_ / 64, H_ / 64), 256, 0, stream>>>(w_up, btg_h, btg_l, H_, FF_, FF_);
  gemm_mfma<<<1024, 256, 0, stream>>>(xh, xl, nullptr, btg_h, btg_l, act, act, NQ_, FF_, H_, 2, 0, 2);
  // down GEMM: split-K=2 (grid 512), f32-A split path, bf16x2, partials + residual
  wsplit_t<<<dim3(H_ / 64, FF_ / 64), 256, 0, stream>>>(w_down, btg_h, btg_l, FF_, H_, H_);
  gemm_mfma<<<512, 256, 0, stream>>>(nullptr, nullptr, act, btg_h, btg_l, dn_p, nullptr, NQ_, H_, FF_, 0, 2, 2);
  reduce_n<<<4096, 256, 0, stream>>>(dn_p, hs2, out_o, 2);

  aux_write<<<8192, 256, 0, stream>>>(out_o, auxc, pruned, aux_bit, map_full, aux_o);
}

// Round 16
// 1204.079 us; speedup vs baseline: 1.0519x; 1.0519x over previous
//
#include <hip/hip_runtime.h>
#include <math.h>

// ---------------- problem constants ----------------
constexpr int S_    = 4096;
constexpr int NKV   = 2048;
constexpr int NAUX  = 512;
constexpr int NNEW  = 1536;
constexpr int H_    = 2048;
constexpr int NH_   = 16;
constexpr int HD_   = 128;
constexpr int FF_   = 8192;
constexpr int NQ_   = 2048;   // NNEW + NAUX
constexpr int NK_   = 4096;   // NKV + NQ
constexpr int PRUNE = 409;
constexpr float EPSF = 1e-6f;

typedef __attribute__((ext_vector_type(8))) short bf16x8;
typedef __attribute__((ext_vector_type(16))) float f32x16;

__device__ __forceinline__ ushort f2bf(float x) {
  union { float f; unsigned u; } a; a.f = x;
  unsigned r = a.u + 0x7fffu + ((a.u >> 16) & 1u);
  return (ushort)(r >> 16);
}
__device__ __forceinline__ float bf2f(ushort h) {
  union { unsigned u; float f; } a; a.u = ((unsigned)h) << 16;
  return a.f;
}
__device__ __forceinline__ unsigned cvt_pk_bf16(float a, float b) {
  unsigned r;
  asm("v_cvt_pk_bf16_f32 %0, %1, %2" : "=v"(r) : "v"(a), "v"(b));
  return r;
}
__device__ __forceinline__ float bflo(unsigned w) { union { unsigned u; float f; } x; x.u = w << 16; return x.f; }
__device__ __forceinline__ float bfhi(unsigned w) { union { unsigned u; float f; } x; x.u = w & 0xffff0000u; return x.f; }

// async global->LDS, 16B per lane. LDS dest = base + lane*16 (HW); global src per-lane.
__device__ __forceinline__ void gload16(const ushort* g, ushort* l) {
  __builtin_amdgcn_global_load_lds(
      (const __attribute__((address_space(1))) unsigned int*)g,
      (__attribute__((address_space(3))) unsigned int*)l, 16, 0, 0);
}

// tiled bf16-plane layout: [row>>7][k>>5][(k>>3)&3][row&127][k&7]
// each 128x32 tile = 8KB contiguous = the exact LDS staging image (chunk-major).
// consecutive k-step tiles of one panel are contiguous (16KB per BK=64 pair).
__device__ __forceinline__ size_t tileoff(int row, int k, int K) {
  return ((size_t)((row >> 7) * (K >> 5) + (k >> 5)) << 12)
       + (size_t)((((k >> 3) & 3) << 10) + ((row & 127) << 3) + (k & 7));
}

// ---------------- index prep ----------------
__global__ __launch_bounds__(256) void prep_build(
    const int* __restrict__ kv_idxs, const int* __restrict__ aux_idxs,
    const int* __restrict__ new_idxs, const int* __restrict__ positions,
    int* hs_idxs, int* q_pos, int* key_tok, int* k_pos,
    int* map_full, int* in_hs, int* aux_bit, int* pruned_bit, int* last_hs)
{
  int t = blockIdx.x * 256 + threadIdx.x;     // grid covers 4096
  if (t < S_) { map_full[t] = 0; in_hs[t] = 0; aux_bit[t] = 0; pruned_bit[t] = 0; }
  if (t < NQ_) {
    int tok = (t < NNEW) ? new_idxs[t] : aux_idxs[t - NNEW];
    hs_idxs[t] = tok;
    q_pos[t] = positions[tok];
  }
  if (t < NK_) {
    int tok;
    if (t < NKV) tok = kv_idxs[t];
    else { int i = t - NKV; tok = (i < NNEW) ? new_idxs[i] : aux_idxs[i - NNEW]; }
    key_tok[t] = tok;
    k_pos[t] = positions[tok];
  }
  if (t < NNEW && new_idxs[t] == S_ - 1) last_hs[0] = t;
}

__global__ __launch_bounds__(256) void prep_scatter(
    const int* __restrict__ hs_idxs, const int* __restrict__ aux_idxs,
    int* map_full, int* in_hs, int* aux_bit)
{
  int t = blockIdx.x * 256 + threadIdx.x;
  if (t < NQ_) { int tok = hs_idxs[t]; map_full[tok] = t; in_hs[tok] = 1; }
  else if (t < NQ_ + NAUX) { aux_bit[aux_idxs[t - NQ_]] = 1; }
}

// Prune semantics of the reference (bug-compatible): see previous session note.
__global__ __launch_bounds__(256) void prune_set(
    const int* __restrict__ kv_idxs, int* __restrict__ pruned_bit)
{
  int t = blockIdx.x * 256 + threadIdx.x;
  if (t < PRUNE - 1) pruned_bit[kv_idxs[t]] = 1;
  if (t == PRUNE - 1) pruned_bit[S_ - 1] = 1;
}

// ---------------- hs = concat(hidden_states, aux_cache[aux_idxs]) ----------------
__global__ __launch_bounds__(256) void build_hs(
    const float* __restrict__ hidden, const float* __restrict__ auxc,
    const int* __restrict__ aux_idxs, float* __restrict__ hs)
{
  int gid = blockIdx.x * 256 + threadIdx.x;   // NQ*H/4 float4
  int c4 = gid & 511;                          // H/4 = 512
  int i  = gid >> 9;
  const float4* src;
  if (i < NNEW) src = (const float4*)hidden + (size_t)i * 512 + c4;
  else          src = (const float4*)auxc + (size_t)aux_idxs[i - NNEW] * 512 + c4;
  ((float4*)hs)[gid] = *src;
}

// ---------------- rmsnorm -> tiled bf16 hi/lo planes ----------------
__global__ __launch_bounds__(256) void rmsnorm_split(
    const float* __restrict__ in, const float* __restrict__ w,
    ushort* __restrict__ oh, ushort* __restrict__ ol)
{
  int row = blockIdx.x, t = threadIdx.x;
  const float4* r4 = (const float4*)(in + (size_t)row * H_);
  const float4* w4 = (const float4*)w;
  float ss = 0.f;
  float4 v0 = r4[t], v1 = r4[t + 256];
  ss += v0.x*v0.x + v0.y*v0.y + v0.z*v0.z + v0.w*v0.w;
  ss += v1.x*v1.x + v1.y*v1.y + v1.z*v1.z + v1.w*v1.w;
  __shared__ float red[256];
  red[t] = ss; __syncthreads();
  for (int s = 128; s > 0; s >>= 1) { if (t < s) red[t] += red[t + s]; __syncthreads(); }
  float inv = rsqrtf(red[0] / (float)H_ + EPSF);
  float4 wv0 = w4[t], wv1 = w4[t + 256];
  float f[8];
  f[0] = v0.x*inv*wv0.x; f[1] = v0.y*inv*wv0.y; f[2] = v0.z*inv*wv0.z; f[3] = v0.w*inv*wv0.w;
  f[4] = v1.x*inv*wv1.x; f[5] = v1.y*inv*wv1.y; f[6] = v1.z*inv*wv1.z; f[7] = v1.w*inv*wv1.w;
  ushort4 h0, l0, h1, l1;
  h0.x = f2bf(f[0]); l0.x = f2bf(f[0] - bf2f(h0.x));
  h0.y = f2bf(f[1]); l0.y = f2bf(f[1] - bf2f(h0.y));
  h0.z = f2bf(f[2]); l0.z = f2bf(f[2] - bf2f(h0.z));
  h0.w = f2bf(f[3]); l0.w = f2bf(f[3] - bf2f(h0.w));
  h1.x = f2bf(f[4]); l1.x = f2bf(f[4] - bf2f(h1.x));
  h1.y = f2bf(f[5]); l1.y = f2bf(f[5] - bf2f(h1.y));
  h1.z = f2bf(f[6]); l1.z = f2bf(f[6] - bf2f(h1.z));
  h1.w = f2bf(f[7]); l1.w = f2bf(f[7] - bf2f(h1.w));
  size_t o0 = tileoff(row, t * 4, H_);
  size_t o1 = tileoff(row, 1024 + t * 4, H_);
  *(ushort4*)(oh + o0) = h0; *(ushort4*)(ol + o0) = l0;
  *(ushort4*)(oh + o1) = h1; *(ushort4*)(ol + o1) = l1;
}

// ---------------- weight transpose + bf16 hi/lo split (tiled output) ----------------
// W[K][.] f32 (row stride ld) -> Th/Tl tiled [N-panel][kstep][chunk][row][8].
// grid = (N/64, K/64).
__global__ __launch_bounds__(256) void wsplit_t(
    const float* __restrict__ Wsrc, ushort* __restrict__ Th, ushort* __restrict__ Tl,
    int K, int N, int ld)
{
  __shared__ float tile[64][65];
  const int bn = blockIdx.x * 64, bk = blockIdx.y * 64;
  const int t = threadIdx.x;
  #pragma unroll
  for (int r = 0; r < 4; ++r) {
    int idx = t + 256 * r;
    int row = idx >> 4, c = (idx & 15) * 4;
    float4 v = *(const float4*)(Wsrc + (size_t)(bk + row) * ld + bn + c);
    tile[row][c] = v.x; tile[row][c+1] = v.y; tile[row][c+2] = v.z; tile[row][c+3] = v.w;
  }
  __syncthreads();
  #pragma unroll
  for (int r = 0; r < 4; ++r) {
    int idx = t + 256 * r;
    int n = bn + (idx >> 4), k = bk + (idx & 15) * 4;
    int kl = k - bk;
    float v0 = tile[kl][n - bn], v1 = tile[kl+1][n - bn], v2 = tile[kl+2][n - bn], v3 = tile[kl+3][n - bn];
    ushort4 h, l;
    h.x = f2bf(v0); l.x = f2bf(v0 - bf2f(h.x));
    h.y = f2bf(v1); l.y = f2bf(v1 - bf2f(h.y));
    h.z = f2bf(v2); l.z = f2bf(v2 - bf2f(h.z));
    h.w = f2bf(v3); l.w = f2bf(v3 - bf2f(h.w));
    size_t off = tileoff(n, k, K);
    *(ushort4*)(Th + off) = h;
    *(ushort4*)(Tl + off) = l;
  }
}

// ---------------- bf16x3 MFMA GEMM, BK=32 (round-14 proven codegen) ----------------
// A: tiled planes Ah/Al, or f32 Af (split in-flight, chunk-major ds_write).
// B: tiled planes Bh/Bl. C f32 row-major.
// epi: 0 plain, 1 C=X+acc, 2 C=silu(X)*acc, 3 QKV-fused de-concat (N=3*2048).
// split>=2: K divided into `split` chunks; chunk c writes partials to C + c*M*N.
__global__ __launch_bounds__(256) void gemm_mfma(
    const ushort* __restrict__ Ah, const ushort* __restrict__ Al,
    const float* __restrict__ Af,
    const ushort* __restrict__ Bh, const ushort* __restrict__ Bl,
    float* __restrict__ C, const float* __restrict__ X,
    int M, int N, int K, int epi, int split)
{
  __shared__ __align__(16) ushort sAh[4096];
  __shared__ __align__(16) ushort sAl[4096];
  __shared__ __align__(16) ushort sBh[4096];
  __shared__ __align__(16) ushort sBl[4096];
  int flat = blockIdx.x;
  int kbeg = 0, kend = K;
  float* Cout = C;
  if (split >= 2) {
    int nb = gridDim.x / split;
    int chunk = flat / nb;
    flat -= chunk * nb;
    int kc = K / split;
    kbeg = chunk * kc; kend = kbeg + kc;
    Cout = C + (size_t)chunk * M * N;
  }
  const int MB = M >> 7;
  const int cM = MB >> 3;
  const int xcd = flat & 7, idxr = flat >> 3;
  const int byi = xcd * cM + (idxr % cM);      // A panel: XCD-resident slab
  const int bxi = idxr / cM;                   // B panel: streamed (L3)
  const int bm = byi * 128, bn = bxi * 128;
  const int t = threadIdx.x;
  const int lane = t & 63;
  const int wid = t >> 6;
  const int wr = wid >> 1, wc = wid & 1;
  const int fr = lane & 31;
  const int kg = lane >> 5;
  const int ub0 = wid * 128;
  const int Ksteps = K >> 5;

  f32x16 acc[2][2];
  #pragma unroll
  for (int mi = 0; mi < 2; ++mi)
    #pragma unroll
    for (int ni = 0; ni < 2; ++ni)
      #pragma unroll
      for (int r = 0; r < 16; ++r) acc[mi][ni][r] = 0.f;

  for (int k0 = kbeg; k0 < kend; k0 += 32) {
    const int ks = k0 >> 5;
    const size_t tB = ((size_t)(bxi * Ksteps + ks)) << 12;
    if (Af) {
      #pragma unroll
      for (int r = 0; r < 2; ++r) {
        int u = t + 256 * r;
        int row = u >> 2, ch = u & 3;
        const float* s0 = Af + (size_t)(bm + row) * K + k0 + ch * 8;
        float4 v0 = *(const float4*)s0, v1 = *(const float4*)(s0 + 4);
        float f[8] = {v0.x,v0.y,v0.z,v0.w,v1.x,v1.y,v1.z,v1.w};
        union { ushort u16[8]; uint4 q; } Hh, Ll;
        #pragma unroll
        for (int j = 0; j < 8; ++j) {
          ushort hh = f2bf(f[j]);
          Hh.u16[j] = hh; Ll.u16[j] = f2bf(f[j] - bf2f(hh));
        }
        *(uint4*)&sAh[ch * 1024 + row * 8] = Hh.q;
        *(uint4*)&sAl[ch * 1024 + row * 8] = Ll.q;
      }
    } else {
      const size_t tA = ((size_t)(byi * Ksteps + ks)) << 12;
      const ushort* a0 = Ah + tA;
      const ushort* a1 = Al + tA;
      gload16(a0 + (size_t)(ub0 + lane) * 8,      sAh + ub0 * 8);
      gload16(a0 + (size_t)(ub0 + 64 + lane) * 8, sAh + (ub0 + 64) * 8);
      gload16(a1 + (size_t)(ub0 + lane) * 8,      sAl + ub0 * 8);
      gload16(a1 + (size_t)(ub0 + 64 + lane) * 8, sAl + (ub0 + 64) * 8);
    }
    {
      const ushort* b0 = Bh + tB;
      const ushort* b1 = Bl + tB;
      gload16(b0 + (size_t)(ub0 + lane) * 8,      sBh + ub0 * 8);
      gload16(b0 + (size_t)(ub0 + 64 + lane) * 8, sBh + (ub0 + 64) * 8);
      gload16(b1 + (size_t)(ub0 + lane) * 8,      sBl + ub0 * 8);
      gload16(b1 + (size_t)(ub0 + 64 + lane) * 8, sBl + (ub0 + 64) * 8);
    }
    __syncthreads();
    #pragma unroll
    for (int ksl = 0; ksl < 2; ++ksl) {
      const int co = (ksl * 2 + kg) * 1024;
      bf16x8 ah[2], al[2], bh[2], bl[2];
      #pragma unroll
      for (int mi = 0; mi < 2; ++mi) {
        ah[mi] = *(const bf16x8*)&sAh[co + (wr * 64 + mi * 32 + fr) * 8];
        al[mi] = *(const bf16x8*)&sAl[co + (wr * 64 + mi * 32 + fr) * 8];
        bh[mi] = *(const bf16x8*)&sBh[co + (wc * 64 + mi * 32 + fr) * 8];
        bl[mi] = *(const bf16x8*)&sBl[co + (wc * 64 + mi * 32 + fr) * 8];
      }
      #pragma unroll
      for (int mi = 0; mi < 2; ++mi)
        #pragma unroll
        for (int ni = 0; ni < 2; ++ni) {
          acc[mi][ni] = __builtin_amdgcn_mfma_f32_32x32x16_bf16(ah[mi], bh[ni], acc[mi][ni], 0, 0, 0);
          acc[mi][ni] = __builtin_amdgcn_mfma_f32_32x32x16_bf16(ah[mi], bl[ni], acc[mi][ni], 0, 0, 0);
          acc[mi][ni] = __builtin_amdgcn_mfma_f32_32x32x16_bf16(al[mi], bh[ni], acc[mi][ni], 0, 0, 0);
        }
    }
    __syncthreads();
  }
  #pragma unroll
  for (int mi = 0; mi < 2; ++mi) {
    #pragma unroll
    for (int ni = 0; ni < 2; ++ni) {
      #pragma unroll
      for (int r = 0; r < 16; ++r) {
        int row = bm + wr * 64 + mi * 32 + (r & 3) + 8 * (r >> 2) + 4 * kg;
        int col = bn + wc * 64 + ni * 32 + fr;
        float v = acc[mi][ni][r];
        size_t idx;
        if (epi == 3) {
          int mtx = col >> 11, cc = col & 2047;
          idx = ((size_t)mtx * M + row) * 2048 + cc;
        } else {
          idx = (size_t)row * N + col;
          if (split < 2) {
            if (epi == 1) v += X[idx];
            else if (epi == 2) { float g = X[idx]; v = (g / (1.f + expf(-g))) * v; }
          }
        }
        Cout[idx] = v;
      }
    }
  }
}

// ---------------- FFN GEMM: bf16x2, BK=64 (drain-amortized) ----------------
// Round-15 diagnosis: k-step cost is a FIXED drain latency (removing 33% of
// work changed nothing). BK=64 halves the number of drains. bt2 keeps LDS at
// 48KB (A hi/lo 32KB + B-hi 16KB). Hardcoded paths (no runtime branches).
// A: planes Ah/Al or f32 Af. B: Bh only (err = a*bl ~2^-9 rel, validated r15).
// epi: 0 plain, 2 C=silu(X)*acc. split>=2 as in gemm_mfma.
__global__ __launch_bounds__(256) void gemm_ffn64(
    const ushort* __restrict__ Ah, const ushort* __restrict__ Al,
    const float* __restrict__ Af,
    const ushort* __restrict__ Bh,
    float* __restrict__ C, const float* __restrict__ X,
    int M, int N, int K, int epi, int split)
{
  __shared__ __align__(16) ushort sAh[8192];
  __shared__ __align__(16) ushort sAl[8192];
  __shared__ __align__(16) ushort sBh[8192];
  int flat = blockIdx.x;
  int kbeg = 0, kend = K;
  float* Cout = C;
  if (split >= 2) {
    int nb = gridDim.x / split;
    int chunk = flat / nb;
    flat -= chunk * nb;
    int kc = K / split;
    kbeg = chunk * kc; kend = kbeg + kc;
    Cout = C + (size_t)chunk * M * N;
  }
  const int MB = M >> 7;
  const int cM = MB >> 3;
  const int xcd = flat & 7, idxr = flat >> 3;
  const int byi = xcd * cM + (idxr % cM);      // A panel: XCD-resident slab
  const int bxi = idxr / cM;                   // B panel: streamed (L3)
  const int bm = byi * 128, bn = bxi * 128;
  const int t = threadIdx.x;
  const int lane = t & 63;
  const int wid = t >> 6;
  const int wr = wid >> 1, wc = wid & 1;
  const int fr = lane & 31;
  const int kg = lane >> 5;
  const int ub2 = wid * 256;                   // 1024 idx-units per 2-tile pair
  const int Ksteps = K >> 5;                   // 32-k tile units

  f32x16 acc[2][2];
  #pragma unroll
  for (int mi = 0; mi < 2; ++mi)
    #pragma unroll
    for (int ni = 0; ni < 2; ++ni)
      #pragma unroll
      for (int r = 0; r < 16; ++r) acc[mi][ni][r] = 0.f;

  for (int k0 = kbeg; k0 < kend; k0 += 64) {
    const int ks = k0 >> 5;                    // first of 2 consecutive tiles
    const size_t tB = ((size_t)(bxi * Ksteps + ks)) << 12;
    if (Af) {
      // stage A f32 128x64 -> chunk-major hi/lo images (2 tiles of 4 chunks)
      #pragma unroll
      for (int r = 0; r < 4; ++r) {
        int u = t + 256 * r;                   // 0..1023
        int row = u >> 3, ch = u & 7;          // 8 chunks of 8 cols
        const float* s0 = Af + (size_t)(bm + row) * K + k0 + ch * 8;
        float4 v0 = *(const float4*)s0, v1 = *(const float4*)(s0 + 4);
        float f[8] = {v0.x,v0.y,v0.z,v0.w,v1.x,v1.y,v1.z,v1.w};
        union { ushort u16[8]; uint4 q; } Hh, Ll;
        #pragma unroll
        for (int j = 0; j < 8; ++j) {
          ushort hh = f2bf(f[j]);
          Hh.u16[j] = hh; Ll.u16[j] = f2bf(f[j] - bf2f(hh));
        }
        int dst = (ch >> 2) * 4096 + (ch & 3) * 1024 + row * 8;
        *(uint4*)&sAh[dst] = Hh.q;
        *(uint4*)&sAl[dst] = Ll.q;
      }
    } else {
      const size_t tA = ((size_t)(byi * Ksteps + ks)) << 12;
      const ushort* a0 = Ah + tA;
      const ushort* a1 = Al + tA;
      #pragma unroll
      for (int r = 0; r < 4; ++r) {
        gload16(a0 + (size_t)(ub2 + r * 64 + lane) * 8, sAh + (ub2 + r * 64) * 8);
        gload16(a1 + (size_t)(ub2 + r * 64 + lane) * 8, sAl + (ub2 + r * 64) * 8);
      }
    }
    {
      const ushort* b0 = Bh + tB;
      #pragma unroll
      for (int r = 0; r < 4; ++r)
        gload16(b0 + (size_t)(ub2 + r * 64 + lane) * 8, sBh + (ub2 + r * 64) * 8);
    }
    __syncthreads();
    #pragma unroll
    for (int ksl = 0; ksl < 4; ++ksl) {
      const int co = (ksl >> 1) * 4096 + (((ksl & 1) * 2 + kg)) * 1024;
      bf16x8 ah[2], al[2], bh[2];
      #pragma unroll
      for (int mi = 0; mi < 2; ++mi) {
        ah[mi] = *(const bf16x8*)&sAh[co + (wr * 64 + mi * 32 + fr) * 8];
        al[mi] = *(const bf16x8*)&sAl[co + (wr * 64 + mi * 32 + fr) * 8];
        bh[mi] = *(const bf16x8*)&sBh[co + (wc * 64 + mi * 32 + fr) * 8];
      }
      __builtin_amdgcn_s_setprio(1);
      #pragma unroll
      for (int mi = 0; mi < 2; ++mi)
        #pragma unroll
        for (int ni = 0; ni < 2; ++ni) {
          acc[mi][ni] = __builtin_amdgcn_mfma_f32_32x32x16_bf16(ah[mi], bh[ni], acc[mi][ni], 0, 0, 0);
          acc[mi][ni] = __builtin_amdgcn_mfma_f32_32x32x16_bf16(al[mi], bh[ni], acc[mi][ni], 0, 0, 0);
        }
      __builtin_amdgcn_s_setprio(0);
    }
    __syncthreads();
  }
  #pragma unroll
  for (int mi = 0; mi < 2; ++mi) {
    #pragma unroll
    for (int ni = 0; ni < 2; ++ni) {
      #pragma unroll
      for (int r = 0; r < 16; ++r) {
        int row = bm + wr * 64 + mi * 32 + (r & 3) + 8 * (r >> 2) + 4 * kg;
        int col = bn + wc * 64 + ni * 32 + fr;
        float v = acc[mi][ni][r];
        size_t idx = (size_t)row * N + col;
        if (split < 2) {
          if (epi == 1) v += X[idx];
          else if (epi == 2) { float g = X[idx]; v = (g / (1.f + expf(-g))) * v; }
        }
        Cout[idx] = v;
      }
    }
  }
}

// ---------------- o = sum(parts[0..np)) + x (split-K reduce + residual) ----------------
__global__ __launch_bounds__(256) void reduce_n(
    const float* __restrict__ parts, const float* __restrict__ x,
    float* __restrict__ o, int np)
{
  int g = blockIdx.x * 256 + threadIdx.x;     // NQ*H/4 float4
  float4 vx = ((const float4*)x)[g];
  float4 vo = vx;
  for (int p = 0; p < np; ++p) {
    float4 vp = ((const float4*)(parts + (size_t)p * NQ_ * H_))[g];
    vo.x += vp.x; vo.y += vp.y; vo.z += vp.z; vo.w += vp.w;
  }
  ((float4*)o)[g] = vo;
}

// ---------------- RoPE in-place on q and k ----------------
__global__ __launch_bounds__(256) void rope_k(
    float* __restrict__ qb, float* __restrict__ kb, const int* __restrict__ q_pos)
{
  int gid = blockIdx.x * 256 + threadIdx.x;   // NQ*NH*64
  int d = gid & 63;
  int h = (gid >> 6) & 15;
  int i = gid >> 10;
  int p = q_pos[i];
  double ang = (double)p * exp((double)d * -0.14391156831212787);
  float c = (float)cos(ang), s = (float)sin(ang);
  size_t ia = (size_t)i * H_ + h * HD_ + d;
  size_t ib = ia + 64;
  float qa = qb[ia], qbv = qb[ib];
  qb[ia] = qa * c - qbv * s;
  qb[ib] = qbv * c + qa * s;
  float ka = kb[ia], kbv = kb[ib];
  kb[ia] = ka * c - kbv * s;
  kb[ib] = kbv * c + ka * s;
}

// ---------------- K (hi/lo) + V^T (hi) bf16 planes ----------------
// kh/kl: [NH][NK][HD]; vth: TILE-MAJOR [NH][NK/64][HD][64].  grid = (NK/64, NH)
__global__ __launch_bounds__(256) void fill_kv_planes(
    const float* __restrict__ kcache, const float* __restrict__ vcache,
    const float* __restrict__ kb, const float* __restrict__ vb,
    const int* __restrict__ kv_idxs,
    ushort* __restrict__ kh, ushort* __restrict__ kl,
    ushort* __restrict__ vth)
{
  __shared__ float vt[64][133];
  const int h = blockIdx.y;
  const int kbase = blockIdx.x * 64;
  const int t = threadIdx.x;
  #pragma unroll
  for (int r = 0; r < 8; ++r) {
    int idx = t + 256 * r;                     // 2048 float4
    int key = idx >> 5, d4 = idx & 31;
    int j = kbase + key;
    float4 kv, vv;
    if (j < NKV) {
      int tok = kv_idxs[j];
      size_t src = ((size_t)h * S_ + tok) * 32 + d4;
      kv = ((const float4*)kcache)[src];
      vv = ((const float4*)vcache)[src];
    } else {
      int i = j - NKV;
      size_t src = (size_t)i * 512 + h * 32 + d4;
      kv = ((const float4*)kb)[src];
      vv = ((const float4*)vb)[src];
    }
    ushort4 hh, ll;
    hh.x = f2bf(kv.x); ll.x = f2bf(kv.x - bf2f(hh.x));
    hh.y = f2bf(kv.y); ll.y = f2bf(kv.y - bf2f(hh.y));
    hh.z = f2bf(kv.z); ll.z = f2bf(kv.z - bf2f(hh.z));
    hh.w = f2bf(kv.w); ll.w = f2bf(kv.w - bf2f(hh.w));
    size_t dst = ((size_t)(h * NK_ + j)) * 128 + d4 * 4;
    *(ushort4*)(kh + dst) = hh;
    *(ushort4*)(kl + dst) = ll;
    vt[key][d4 * 4 + 0] = vv.x; vt[key][d4 * 4 + 1] = vv.y;
    vt[key][d4 * 4 + 2] = vv.z; vt[key][d4 * 4 + 3] = vv.w;
  }
  __syncthreads();
  #pragma unroll
  for (int r = 0; r < 8; ++r) {
    int idx = t + 256 * r;                     // 2048 groups of 4 keys
    int d = idx >> 4, kq = (idx & 15) * 4;
    float v0 = vt[kq + 0][d], v1 = vt[kq + 1][d], v2 = vt[kq + 2][d], v3 = vt[kq + 3][d];
    ushort4 hh;
    hh.x = f2bf(v0); hh.y = f2bf(v1); hh.z = f2bf(v2); hh.w = f2bf(v3);
    size_t dst = (((size_t)h * 64 + blockIdx.x) * 128 + d) * 64 + kq;
    *(ushort4*)(vth + dst) = hh;
  }
}

// ---------------- MFMA flash attention (4-way key-split, grid 1024, LPT order) ----------------
// (benched round-11 structure — unchanged)
struct MergeLDS4 { float buf[2][32][132]; float ml[2][2][32]; };

__global__ __launch_bounds__(256, 2) void flash_mfma(
    const float* __restrict__ qb, const ushort* __restrict__ khg,
    const ushort* __restrict__ klg, const ushort* __restrict__ vthg,
    const int* __restrict__ q_pos, const int* __restrict__ k_pos,
    ushort* __restrict__ ctxh, ushort* __restrict__ ctxl)
{
  __shared__ MergeLDS4 U;
  const int b = blockIdx.x;
  const int h = (b & 7) * 2 + ((b >> 3) & 1);  // 2 heads per XCD slab
  const int qb32 = 63 - (b >> 4);              // heaviest blocks first (LPT)
  const int q0 = qb32 * 32;
  const int t = threadIdx.x;
  const int wk = t >> 6, lane = t & 63;
  const int kg = lane >> 5;
  const int qc = lane & 31;
  const int qi = q0 + qc;
  const float scale = 0.08838834764831844f;    // 1/sqrt(128)

  bf16x8 qh[8], ql[8];
  {
    const float4* q4 = (const float4*)qb;
    #pragma unroll
    for (int s = 0; s < 8; ++s) {
      size_t a = (size_t)qi * 512 + h * 32 + s * 4 + kg * 2;
      float4 f0 = q4[a], f1 = q4[a + 1];
      float f[8] = {f0.x, f0.y, f0.z, f0.w, f1.x, f1.y, f1.z, f1.w};
      union { ushort u[8]; bf16x8 v; } Hq, Lq;
      #pragma unroll
      for (int j = 0; j < 8; ++j) {
        float qs = f[j] * scale;
        ushort hh = f2bf(qs);
        Hq.u[j] = hh; Lq.u[j] = f2bf(qs - bf2f(hh));
      }
      qh[s] = Hq.v; ql[s] = Lq.v;
    }
  }
  const int qp = q_pos[qi];
  const int wave_qmin = __shfl(qp, 0);
  const int wave_qmax = __shfl(qp, 31);       // q ascend within 32-block

  const ushort* kh_base = khg + (size_t)h * NK_ * 128;
  const ushort* kl_base = klg + (size_t)h * NK_ * 128;
  const ushort* vt_base = vthg + (size_t)h * NK_ * 128;   // [NK/64][128][64]

  f32x16 acc[4];
  #pragma unroll
  for (int f = 0; f < 4; ++f)
    #pragma unroll
    for (int r = 0; r < 16; ++r) acc[f][r] = 0.f;
  float m_run = -INFINITY, l_run = 0.f;

  for (int c = wk; c < NK_ / 32; c += 4) {     // interleaved 32-key chunks
    const int krow0 = c * 32;
    const int kpv = k_pos[krow0 + qc];
    if (__shfl(kpv, 0) > wave_qmax) continue;  // chunk fully masked
    const bool needmask = (__shfl(kpv, 31) > wave_qmin);

    f32x16 sA, sB;
    #pragma unroll
    for (int r = 0; r < 16; ++r) { sA[r] = 0.f; sB[r] = 0.f; }
    const ushort* krow = kh_base + (size_t)(krow0 + qc) * 128 + kg * 8;
    const ushort* lrow = kl_base + (size_t)(krow0 + qc) * 128 + kg * 8;
    __builtin_amdgcn_s_setprio(1);
    #pragma unroll
    for (int s = 0; s < 8; ++s) {
      bf16x8 khf = *(const bf16x8*)(krow + s * 16);
      bf16x8 klf = *(const bf16x8*)(lrow + s * 16);
      sA = __builtin_amdgcn_mfma_f32_32x32x16_bf16(khf, qh[s], sA, 0, 0, 0);
      sB = __builtin_amdgcn_mfma_f32_32x32x16_bf16(khf, ql[s], sB, 0, 0, 0);
      sB = __builtin_amdgcn_mfma_f32_32x32x16_bf16(klf, qh[s], sB, 0, 0, 0);
    }
    __builtin_amdgcn_s_setprio(0);
    // V fragments from tile-major layout (issued early, hide under softmax)
    bf16x8 vf[2][4];
    {
      const ushort* vtile = vt_base + (size_t)(c >> 1) * 8192;   // 128*64
      #pragma unroll
      for (int ks = 0; ks < 2; ++ks) {
        const int kc = (c & 1) * 32 + ks * 16 + kg * 8;          // within-tile key
        #pragma unroll
        for (int f = 0; f < 4; ++f)
          vf[ks][f] = *(const bf16x8*)(vtile + (f * 32 + qc) * 64 + kc);
      }
    }
    float sc[16];
    #pragma unroll
    for (int r = 0; r < 16; ++r) sc[r] = sA[r] + sB[r];
    if (needmask) {
      #pragma unroll
      for (int r = 0; r < 16; ++r) {
        int crow = (r & 3) + 8 * (r >> 2) + 4 * kg;
        sc[r] = (__shfl(kpv, crow) <= qp) ? sc[r] : -INFINITY;
      }
    }
    float mloc = sc[0];
    #pragma unroll
    for (int r = 1; r < 16; ++r) mloc = fmaxf(mloc, sc[r]);
    mloc = fmaxf(mloc, __shfl_xor(mloc, 32));
    float m_new = fmaxf(m_run, mloc);
    float mexp = (m_new == -INFINITY) ? 0.f : m_new;
    if (__any(m_new > m_run)) {
      float aa = __expf(m_run - mexp);
      l_run *= aa;
      #pragma unroll
      for (int f = 0; f < 4; ++f)
        #pragma unroll
        for (int r = 0; r < 16; ++r) acc[f][r] *= aa;
    }
    m_run = m_new;
    float p[16]; float psum = 0.f;
    #pragma unroll
    for (int r = 0; r < 16; ++r) { p[r] = __expf(sc[r] - mexp); psum += p[r]; }
    psum += __shfl_xor(psum, 32);
    l_run += psum;
    bf16x8 pfh[2], pfl[2];
    #pragma unroll
    for (int sl = 0; sl < 2; ++sl) {
      const float* pp = p + sl * 8;
      unsigned a0 = cvt_pk_bf16(pp[0], pp[1]);
      unsigned a1 = cvt_pk_bf16(pp[2], pp[3]);
      unsigned b0 = cvt_pk_bf16(pp[4], pp[5]);
      unsigned b1 = cvt_pk_bf16(pp[6], pp[7]);
      unsigned a0x = (unsigned)__shfl_xor((int)a0, 32);
      unsigned a1x = (unsigned)__shfl_xor((int)a1, 32);
      unsigned b0x = (unsigned)__shfl_xor((int)b0, 32);
      unsigned b1x = (unsigned)__shfl_xor((int)b1, 32);
      union { unsigned wd[4]; bf16x8 v; } PH, PL;
      PH.wd[0] = kg ? b0x : a0;
      PH.wd[1] = kg ? b1x : a1;
      PH.wd[2] = kg ? b0 : a0x;
      PH.wd[3] = kg ? b1 : a1x;
      float r0 = pp[0] - bflo(a0), r1 = pp[1] - bfhi(a0);
      float r2 = pp[2] - bflo(a1), r3 = pp[3] - bfhi(a1);
      float r4 = pp[4] - bflo(b0), r5 = pp[5] - bfhi(b0);
      float r6 = pp[6] - bflo(b1), r7 = pp[7] - bfhi(b1);
      unsigned c0 = cvt_pk_bf16(r0, r1);
      unsigned c1 = cvt_pk_bf16(r2, r3);
      unsigned d0 = cvt_pk_bf16(r4, r5);
      unsigned d1 = cvt_pk_bf16(r6, r7);
      unsigned c0x = (unsigned)__shfl_xor((int)c0, 32);
      unsigned c1x = (unsigned)__shfl_xor((int)c1, 32);
      unsigned d0x = (unsigned)__shfl_xor((int)d0, 32);
      unsigned d1x = (unsigned)__shfl_xor((int)d1, 32);
      PL.wd[0] = kg ? d0x : c0;
      PL.wd[1] = kg ? d1x : c1;
      PL.wd[2] = kg ? d0 : c0x;
      PL.wd[3] = kg ? d1 : c1x;
      pfh[sl] = PH.v; pfl[sl] = PL.v;
    }
    __builtin_amdgcn_s_setprio(1);
    #pragma unroll
    for (int ks = 0; ks < 2; ++ks) {
      acc[0] = __builtin_amdgcn_mfma_f32_32x32x16_bf16(vf[ks][0], pfh[ks], acc[0], 0, 0, 0);
      acc[1] = __builtin_amdgcn_mfma_f32_32x32x16_bf16(vf[ks][1], pfh[ks], acc[1], 0, 0, 0);
      acc[2] = __builtin_amdgcn_mfma_f32_32x32x16_bf16(vf[ks][2], pfh[ks], acc[2], 0, 0, 0);
      acc[3] = __builtin_amdgcn_mfma_f32_32x32x16_bf16(vf[ks][3], pfh[ks], acc[3], 0, 0, 0);
      acc[0] = __builtin_amdgcn_mfma_f32_32x32x16_bf16(vf[ks][0], pfl[ks], acc[0], 0, 0, 0);
      acc[1] = __builtin_amdgcn_mfma_f32_32x32x16_bf16(vf[ks][1], pfl[ks], acc[1], 0, 0, 0);
      acc[2] = __builtin_amdgcn_mfma_f32_32x32x16_bf16(vf[ks][2], pfl[ks], acc[2], 0, 0, 0);
      acc[3] = __builtin_amdgcn_mfma_f32_32x32x16_bf16(vf[ks][3], pfl[ks], acc[3], 0, 0, 0);
    }
    __builtin_amdgcn_s_setprio(0);
  }

  // ---- 2-stage 4-way merge (guarded online-softmax combine) ----
  if (wk >= 2) {
    const int slot = wk - 2;
    #pragma unroll
    for (int f = 0; f < 4; ++f)
      #pragma unroll
      for (int r = 0; r < 16; ++r) {
        int d = f * 32 + (r & 3) + 8 * (r >> 2) + 4 * kg;
        U.buf[slot][qc][d] = acc[f][r];
      }
    if (kg == 0) { U.ml[slot][0][qc] = m_run; U.ml[slot][1][qc] = l_run; }
  }
  __syncthreads();
  if (wk < 2) {
    const int slot = wk;
    float m2 = U.ml[slot][0][qc];
    float l2 = U.ml[slot][1][qc];
    float mm = fmaxf(m_run, m2);
    float me = (mm == -INFINITY) ? 0.f : mm;
    float a1 = __expf(m_run - me);
    float a2 = __expf(m2 - me);
    #pragma unroll
    for (int f = 0; f < 4; ++f)
      #pragma unroll
      for (int r = 0; r < 16; ++r) {
        int d = f * 32 + (r & 3) + 8 * (r >> 2) + 4 * kg;
        acc[f][r] = acc[f][r] * a1 + U.buf[slot][qc][d] * a2;
      }
    m_run = mm; l_run = l_run * a1 + l2 * a2;
  }
  __syncthreads();
  if (wk == 1) {
    #pragma unroll
    for (int f = 0; f < 4; ++f)
      #pragma unroll
      for (int r = 0; r < 16; ++r) {
        int d = f * 32 + (r & 3) + 8 * (r >> 2) + 4 * kg;
        U.buf[0][qc][d] = acc[f][r];
      }
    if (kg == 0) { U.ml[0][0][qc] = m_run; U.ml[0][1][qc] = l_run; }
  }
  __syncthreads();
  if (wk == 0) {
    float m2 = U.ml[0][0][qc];
    float l2 = U.ml[0][1][qc];
    float mm = fmaxf(m_run, m2);
    float me = (mm == -INFINITY) ? 0.f : mm;
    float a1 = __expf(m_run - me);
    float a2 = __expf(m2 - me);
    float lt = l_run * a1 + l2 * a2;
    float inv = 1.f / lt;
    #pragma unroll
    for (int f = 0; f < 4; ++f)
      #pragma unroll
      for (int rq = 0; rq < 4; ++rq) {
        float o[4];
        #pragma unroll
        for (int j = 0; j < 4; ++j) {
          int d = f * 32 + j + 8 * rq + 4 * kg;
          o[j] = (acc[f][rq * 4 + j] * a1 + U.buf[0][qc][d] * a2) * inv;
        }
        ushort4 hh, ll;
        hh.x = f2bf(o[0]); ll.x = f2bf(o[0] - bf2f(hh.x));
        hh.y = f2bf(o[1]); ll.y = f2bf(o[1] - bf2f(hh.y));
        hh.z = f2bf(o[2]); ll.z = f2bf(o[2] - bf2f(hh.z));
        hh.w = f2bf(o[3]); ll.w = f2bf(o[3] - bf2f(hh.w));
        int d = h * 128 + f * 32 + kg * 4 + rq * 8;
        size_t oidx = tileoff(qi, d, H_);
        *(ushort4*)(ctxh + oidx) = hh;
        *(ushort4*)(ctxl + oidx) = ll;
      }
  }
}

// ---------------- cache scatter outputs ----------------
__global__ __launch_bounds__(256) void write_kv(
    const float* __restrict__ kcache, const float* __restrict__ vcache,
    const float* __restrict__ kb, const float* __restrict__ vb,
    const int* __restrict__ in_hs, const int* __restrict__ map_full,
    float* __restrict__ kc_o, float* __restrict__ vc_o)
{
  int gid = blockIdx.x * 256 + threadIdx.x;   // NH*S*HD/4
  int d4 = gid & 31;
  int s  = (gid >> 5) & (S_ - 1);
  int h  = gid >> 17;
  float4 kv, vv;
  if (in_hs[s]) {
    int i = map_full[s];
    size_t src = (size_t)i * (H_ / 4) + h * 32 + d4;
    kv = ((const float4*)kb)[src];
    vv = ((const float4*)vb)[src];
  } else {
    kv = ((const float4*)kcache)[gid];
    vv = ((const float4*)vcache)[gid];
  }
  ((float4*)kc_o)[gid] = kv;
  ((float4*)vc_o)[gid] = vv;
}

__global__ __launch_bounds__(256) void aux_write(
    const float* __restrict__ outb, const float* __restrict__ auxc,
    const int* __restrict__ pruned_bit, const int* __restrict__ aux_bit,
    const int* __restrict__ map_full, float* __restrict__ aux_o)
{
  int gid = blockIdx.x * 256 + threadIdx.x;   // S*H/4
  int c4 = gid & 511;
  int s  = gid >> 9;
  float4 v;
  if (pruned_bit[s] && !aux_bit[s])
    v = ((const float4*)outb)[(size_t)map_full[s] * 512 + c4];
  else
    v = ((const float4*)auxc)[gid];
  ((float4*)aux_o)[gid] = v;
}

// ---------------- host ----------------
extern "C" void kernel_launch(void* const* d_in, const int* in_sizes, int n_in,
                              void* d_out, int out_size, void* d_ws, size_t ws_size,
                              hipStream_t stream) {
  (void)in_sizes; (void)n_in; (void)out_size; (void)ws_size;
  const float* hidden  = (const float*)d_in[0];
  const float* kcache  = (const float*)d_in[1];
  const float* vcache  = (const float*)d_in[2];
  const float* auxc    = (const float*)d_in[3];
  const int* kv_idxs   = (const int*)d_in[4];
  const int* aux_idxs  = (const int*)d_in[5];
  const int* new_idxs  = (const int*)d_in[6];
  const int* positions = (const int*)d_in[7];
  const float* wq      = (const float*)d_in[8];
  const float* wk      = (const float*)d_in[9];
  const float* wv      = (const float*)d_in[10];
  const float* wo      = (const float*)d_in[11];
  const float* w_gate  = (const float*)d_in[12];
  const float* w_up    = (const float*)d_in[13];
  const float* w_down  = (const float*)d_in[14];
  const float* ln1     = (const float*)d_in[15];
  const float* ln2     = (const float*)d_in[16];

  float* out_o = (float*)d_out;
  float* kc_o  = out_o + (size_t)NQ_ * H_;
  float* vc_o  = kc_o + (size_t)NH_ * S_ * HD_;
  float* aux_o = vc_o + (size_t)NH_ * S_ * HD_;

  // workspace (units of M4 = 4M floats = 16.78 MB), 11 slots + ints.
  // wo split-K=4: partials -> slots 2,3,4,5 (qb/kb/vb/khp dead after flash/write_kv)
  // down split-K=2: partials -> slots 0,1 (hs, x-planes dead by then)
  float* W = (float*)d_ws;
  const size_t M4 = 4194304;                  // NQ*H
  float* hs    = W;
  ushort* xh   = (ushort*)(W + 1 * M4);
  ushort* xl   = xh + (size_t)NQ_ * H_;
  float* qb    = W + 2 * M4;
  float* kb    = W + 3 * M4;
  float* vb    = W + 4 * M4;
  ushort* bt3_h = (ushort*)(W + 5 * M4);      // 3*H*H ushorts (slots 5-6, QKV phase)
  ushort* bt3_l = (ushort*)(W + 8 * M4);      // slots 8-9 (QKV phase only)
  ushort* khp  = (ushort*)(W + 5 * M4);
  ushort* klp  = (ushort*)(W + 6 * M4);
  ushort* vthp = (ushort*)(W + 7 * M4);
  ushort* ctxh = (ushort*)(W + 8 * M4);
  ushort* ctxl = ctxh + (size_t)NQ_ * H_;
  ushort* bt_h = (ushort*)(W + 9 * M4);
  ushort* bt_l = bt_h + (size_t)H_ * H_;
  float* hs2   = W + 10 * M4;
  float* act   = W + 2 * M4;                  // slots 2-5 (FFN phase)
  ushort* btg_h = (ushort*)(W + 6 * M4);      // slots 6-7
  ushort* btg_l = (ushort*)(W + 8 * M4);      // slots 8-9
  float* wo_p  = W + 2 * M4;                  // wo split-4 partials (slots 2-5)
  float* dn_p  = W + 0 * M4;                  // down split-2 partials (slots 0-1)
  int* ip = (int*)(W + 11 * M4);
  int* hs_idxs = ip;           ip += NQ_;
  int* q_pos   = ip;           ip += NQ_;
  int* key_tok = ip;           ip += NK_;
  int* k_pos   = ip;           ip += NK_;
  int* map_full= ip;           ip += S_;
  int* in_hs   = ip;           ip += S_;
  int* aux_bit = ip;           ip += S_;
  int* pruned  = ip;           ip += S_;
  int* last_hs = ip;           ip += 4;

  prep_build<<<16, 256, 0, stream>>>(kv_idxs, aux_idxs, new_idxs, positions,
      hs_idxs, q_pos, key_tok, k_pos, map_full, in_hs, aux_bit, pruned, last_hs);
  prep_scatter<<<10, 256, 0, stream>>>(hs_idxs, aux_idxs, map_full, in_hs, aux_bit);
  prune_set<<<2, 256, 0, stream>>>(kv_idxs, pruned);
  build_hs<<<4096, 256, 0, stream>>>(hidden, auxc, aux_idxs, hs);
  rmsnorm_split<<<NQ_, 256, 0, stream>>>(hs, ln1, xh, xl);

  const dim3 gTH(H_ / 64, H_ / 64);
  // QKV fused: B = concat(wq,wk,wv) panels, N = 6144, epi 3 de-concats C. (bf16x3)
  wsplit_t<<<gTH, 256, 0, stream>>>(wq, bt3_h,                      bt3_l,                      H_, H_, H_);
  wsplit_t<<<gTH, 256, 0, stream>>>(wk, bt3_h + (size_t)H_ * H_,    bt3_l + (size_t)H_ * H_,    H_, H_, H_);
  wsplit_t<<<gTH, 256, 0, stream>>>(wv, bt3_h + (size_t)2 * H_ * H_, bt3_l + (size_t)2 * H_ * H_, H_, H_, H_);
  gemm_mfma<<<768, 256, 0, stream>>>(xh, xl, nullptr, bt3_h, bt3_l, qb, nullptr, NQ_, 3 * H_, H_, 3, 0);

  rope_k<<<8192, 256, 0, stream>>>(qb, kb, q_pos);
  fill_kv_planes<<<dim3(64, 16), 256, 0, stream>>>(kcache, vcache, kb, vb, kv_idxs,
      khp, klp, vthp);

  flash_mfma<<<1024, 256, 0, stream>>>(qb, khp, klp, vthp, q_pos, k_pos, ctxh, ctxl);
  write_kv<<<8192, 256, 0, stream>>>(kcache, vcache, kb, vb, in_hs, map_full, kc_o, vc_o);

  // wo GEMM: split-K=4 (grid 1024), bf16x3, partials in slots 2-5, residual-add
  wsplit_t<<<gTH, 256, 0, stream>>>(wo, bt_h, bt_l, H_, H_, H_);
  gemm_mfma<<<1024, 256, 0, stream>>>(ctxh, ctxl, nullptr, bt_h, bt_l, wo_p, nullptr, NQ_, H_, H_, 0, 4);
  reduce_n<<<4096, 256, 0, stream>>>(wo_p, hs, hs2, 4);
  rmsnorm_split<<<NQ_, 256, 0, stream>>>(hs2, ln2, xh, xl);

  // FFN GEMMs: bf16x2, BK=64 (drain-amortized); B-lo plane unused (still written
  // by wsplit_t into btg_l scratch — harmless).
  wsplit_t<<<dim3(FF_ / 64, H_ / 64), 256, 0, stream>>>(w_gate, btg_h, btg_l, H_, FF_, FF_);
  gemm_ffn64<<<1024, 256, 0, stream>>>(xh, xl, nullptr, btg_h, act, nullptr, NQ_, FF_, H_, 0, 0);
  wsplit_t<<<dim3(FF_ / 64, H_ / 64), 256, 0, stream>>>(w_up, btg_h, btg_l, H_, FF_, FF_);
  gemm_ffn64<<<1024, 256, 0, stream>>>(xh, xl, nullptr, btg_h, act, act, NQ_, FF_, H_, 2, 0);
  // down GEMM: split-K=2 (grid 512), f32-A split path, BK=64, partials + residual
  wsplit_t<<<dim3(H_ / 64, FF_ / 64), 256, 0, stream>>>(w_down, btg_h, btg_l, FF_, H_, H_);
  gemm_ffn64<<<512, 256, 0, stream>>>(nullptr, nullptr, act, btg_h, dn_p, nullptr, NQ_, H_, FF_, 0, 2);
  reduce_n<<<4096, 256, 0, stream>>>(dn_p, hs2, out_o, 2);

  aux_write<<<8192, 256, 0, stream>>>(out_o, auxc, pruned, aux_bit, map_full, aux_o);
}

// Round 17
// 1134.571 us; speedup vs baseline: 1.1163x; 1.0613x over previous
//
#include <hip/hip_runtime.h>
#include <math.h>

// ---------------- problem constants ----------------
constexpr int S_    = 4096;
constexpr int NKV   = 2048;
constexpr int NAUX  = 512;
constexpr int NNEW  = 1536;
constexpr int H_    = 2048;
constexpr int NH_   = 16;
constexpr int HD_   = 128;
constexpr int FF_   = 8192;
constexpr int NQ_   = 2048;   // NNEW + NAUX
constexpr int NK_   = 4096;   // NKV + NQ
constexpr int PRUNE = 409;
constexpr float EPSF = 1e-6f;

typedef __attribute__((ext_vector_type(8))) short bf16x8;
typedef __attribute__((ext_vector_type(16))) float f32x16;

__device__ __forceinline__ ushort f2bf(float x) {
  union { float f; unsigned u; } a; a.f = x;
  unsigned r = a.u + 0x7fffu + ((a.u >> 16) & 1u);
  return (ushort)(r >> 16);
}
__device__ __forceinline__ float bf2f(ushort h) {
  union { unsigned u; float f; } a; a.u = ((unsigned)h) << 16;
  return a.f;
}
__device__ __forceinline__ unsigned cvt_pk_bf16(float a, float b) {
  unsigned r;
  asm("v_cvt_pk_bf16_f32 %0, %1, %2" : "=v"(r) : "v"(a), "v"(b));
  return r;
}
__device__ __forceinline__ float bflo(unsigned w) { union { unsigned u; float f; } x; x.u = w << 16; return x.f; }
__device__ __forceinline__ float bfhi(unsigned w) { union { unsigned u; float f; } x; x.u = w & 0xffff0000u; return x.f; }

// async global->LDS, 16B per lane. LDS dest = base + lane*16 (HW); global src per-lane.
__device__ __forceinline__ void gload16(const ushort* g, ushort* l) {
  __builtin_amdgcn_global_load_lds(
      (const __attribute__((address_space(1))) unsigned int*)g,
      (__attribute__((address_space(3))) unsigned int*)l, 16, 0, 0);
}

// tiled bf16-plane layout: [row>>7][k>>5][(k>>3)&3][row&127][k&7]
// each 128x32 tile = 8KB contiguous = the exact LDS staging image (chunk-major).
// consecutive k-step tiles of one panel are contiguous (16KB per BK=64 pair).
__device__ __forceinline__ size_t tileoff(int row, int k, int K) {
  return ((size_t)((row >> 7) * (K >> 5) + (k >> 5)) << 12)
       + (size_t)((((k >> 3) & 3) << 10) + ((row & 127) << 3) + (k & 7));
}

// ---------------- index prep ----------------
__global__ __launch_bounds__(256) void prep_build(
    const int* __restrict__ kv_idxs, const int* __restrict__ aux_idxs,
    const int* __restrict__ new_idxs, const int* __restrict__ positions,
    int* hs_idxs, int* q_pos, int* key_tok, int* k_pos,
    int* map_full, int* in_hs, int* aux_bit, int* pruned_bit, int* last_hs)
{
  int t = blockIdx.x * 256 + threadIdx.x;     // grid covers 4096
  if (t < S_) { map_full[t] = 0; in_hs[t] = 0; aux_bit[t] = 0; pruned_bit[t] = 0; }
  if (t < NQ_) {
    int tok = (t < NNEW) ? new_idxs[t] : aux_idxs[t - NNEW];
    hs_idxs[t] = tok;
    q_pos[t] = positions[tok];
  }
  if (t < NK_) {
    int tok;
    if (t < NKV) tok = kv_idxs[t];
    else { int i = t - NKV; tok = (i < NNEW) ? new_idxs[i] : aux_idxs[i - NNEW]; }
    key_tok[t] = tok;
    k_pos[t] = positions[tok];
  }
  if (t < NNEW && new_idxs[t] == S_ - 1) last_hs[0] = t;
}

__global__ __launch_bounds__(256) void prep_scatter(
    const int* __restrict__ hs_idxs, const int* __restrict__ aux_idxs,
    int* map_full, int* in_hs, int* aux_bit)
{
  int t = blockIdx.x * 256 + threadIdx.x;
  if (t < NQ_) { int tok = hs_idxs[t]; map_full[tok] = t; in_hs[tok] = 1; }
  else if (t < NQ_ + NAUX) { aux_bit[aux_idxs[t - NQ_]] = 1; }
}

// Prune semantics of the reference (bug-compatible): see previous session note.
__global__ __launch_bounds__(256) void prune_set(
    const int* __restrict__ kv_idxs, int* __restrict__ pruned_bit)
{
  int t = blockIdx.x * 256 + threadIdx.x;
  if (t < PRUNE - 1) pruned_bit[kv_idxs[t]] = 1;
  if (t == PRUNE - 1) pruned_bit[S_ - 1] = 1;
}

// ---------------- hs = concat(hidden_states, aux_cache[aux_idxs]) ----------------
__global__ __launch_bounds__(256) void build_hs(
    const float* __restrict__ hidden, const float* __restrict__ auxc,
    const int* __restrict__ aux_idxs, float* __restrict__ hs)
{
  int gid = blockIdx.x * 256 + threadIdx.x;   // NQ*H/4 float4
  int c4 = gid & 511;                          // H/4 = 512
  int i  = gid >> 9;
  const float4* src;
  if (i < NNEW) src = (const float4*)hidden + (size_t)i * 512 + c4;
  else          src = (const float4*)auxc + (size_t)aux_idxs[i - NNEW] * 512 + c4;
  ((float4*)hs)[gid] = *src;
}

// ---------------- rmsnorm -> tiled bf16 hi/lo planes ----------------
__global__ __launch_bounds__(256) void rmsnorm_split(
    const float* __restrict__ in, const float* __restrict__ w,
    ushort* __restrict__ oh, ushort* __restrict__ ol)
{
  int row = blockIdx.x, t = threadIdx.x;
  const float4* r4 = (const float4*)(in + (size_t)row * H_);
  const float4* w4 = (const float4*)w;
  float ss = 0.f;
  float4 v0 = r4[t], v1 = r4[t + 256];
  ss += v0.x*v0.x + v0.y*v0.y + v0.z*v0.z + v0.w*v0.w;
  ss += v1.x*v1.x + v1.y*v1.y + v1.z*v1.z + v1.w*v1.w;
  __shared__ float red[256];
  red[t] = ss; __syncthreads();
  for (int s = 128; s > 0; s >>= 1) { if (t < s) red[t] += red[t + s]; __syncthreads(); }
  float inv = rsqrtf(red[0] / (float)H_ + EPSF);
  float4 wv0 = w4[t], wv1 = w4[t + 256];
  float f[8];
  f[0] = v0.x*inv*wv0.x; f[1] = v0.y*inv*wv0.y; f[2] = v0.z*inv*wv0.z; f[3] = v0.w*inv*wv0.w;
  f[4] = v1.x*inv*wv1.x; f[5] = v1.y*inv*wv1.y; f[6] = v1.z*inv*wv1.z; f[7] = v1.w*inv*wv1.w;
  ushort4 h0, l0, h1, l1;
  h0.x = f2bf(f[0]); l0.x = f2bf(f[0] - bf2f(h0.x));
  h0.y = f2bf(f[1]); l0.y = f2bf(f[1] - bf2f(h0.y));
  h0.z = f2bf(f[2]); l0.z = f2bf(f[2] - bf2f(h0.z));
  h0.w = f2bf(f[3]); l0.w = f2bf(f[3] - bf2f(h0.w));
  h1.x = f2bf(f[4]); l1.x = f2bf(f[4] - bf2f(h1.x));
  h1.y = f2bf(f[5]); l1.y = f2bf(f[5] - bf2f(h1.y));
  h1.z = f2bf(f[6]); l1.z = f2bf(f[6] - bf2f(h1.z));
  h1.w = f2bf(f[7]); l1.w = f2bf(f[7] - bf2f(h1.w));
  size_t o0 = tileoff(row, t * 4, H_);
  size_t o1 = tileoff(row, 1024 + t * 4, H_);
  *(ushort4*)(oh + o0) = h0; *(ushort4*)(ol + o0) = l0;
  *(ushort4*)(oh + o1) = h1; *(ushort4*)(ol + o1) = l1;
}

// ---------------- weight transpose + bf16 hi/lo split (tiled output) ----------------
// W[K][.] f32 (row stride ld) -> Th/Tl tiled [N-panel][kstep][chunk][row][8].
// grid = (N/64, K/64).
__global__ __launch_bounds__(256) void wsplit_t(
    const float* __restrict__ Wsrc, ushort* __restrict__ Th, ushort* __restrict__ Tl,
    int K, int N, int ld)
{
  __shared__ float tile[64][65];
  const int bn = blockIdx.x * 64, bk = blockIdx.y * 64;
  const int t = threadIdx.x;
  #pragma unroll
  for (int r = 0; r < 4; ++r) {
    int idx = t + 256 * r;
    int row = idx >> 4, c = (idx & 15) * 4;
    float4 v = *(const float4*)(Wsrc + (size_t)(bk + row) * ld + bn + c);
    tile[row][c] = v.x; tile[row][c+1] = v.y; tile[row][c+2] = v.z; tile[row][c+3] = v.w;
  }
  __syncthreads();
  #pragma unroll
  for (int r = 0; r < 4; ++r) {
    int idx = t + 256 * r;
    int n = bn + (idx >> 4), k = bk + (idx & 15) * 4;
    int kl = k - bk;
    float v0 = tile[kl][n - bn], v1 = tile[kl+1][n - bn], v2 = tile[kl+2][n - bn], v3 = tile[kl+3][n - bn];
    ushort4 h, l;
    h.x = f2bf(v0); l.x = f2bf(v0 - bf2f(h.x));
    h.y = f2bf(v1); l.y = f2bf(v1 - bf2f(h.y));
    h.z = f2bf(v2); l.z = f2bf(v2 - bf2f(h.z));
    h.w = f2bf(v3); l.w = f2bf(v3 - bf2f(h.w));
    size_t off = tileoff(n, k, K);
    *(ushort4*)(Th + off) = h;
    *(ushort4*)(Tl + off) = l;
  }
}

// ---------------- bf16x3 MFMA GEMM, BK=32 (round-14 proven codegen) ----------------
// A: tiled planes Ah/Al, or f32 Af (split in-flight, chunk-major ds_write).
// B: tiled planes Bh/Bl. C f32 row-major.
// epi: 0 plain, 1 C=X+acc, 2 C=silu(X)*acc, 3 QKV-fused de-concat (N=3*2048).
// split>=2: K divided into `split` chunks; chunk c writes partials to C + c*M*N.
__global__ __launch_bounds__(256) void gemm_mfma(
    const ushort* __restrict__ Ah, const ushort* __restrict__ Al,
    const float* __restrict__ Af,
    const ushort* __restrict__ Bh, const ushort* __restrict__ Bl,
    float* __restrict__ C, const float* __restrict__ X,
    int M, int N, int K, int epi, int split)
{
  __shared__ __align__(16) ushort sAh[4096];
  __shared__ __align__(16) ushort sAl[4096];
  __shared__ __align__(16) ushort sBh[4096];
  __shared__ __align__(16) ushort sBl[4096];
  int flat = blockIdx.x;
  int kbeg = 0, kend = K;
  float* Cout = C;
  if (split >= 2) {
    int nb = gridDim.x / split;
    int chunk = flat / nb;
    flat -= chunk * nb;
    int kc = K / split;
    kbeg = chunk * kc; kend = kbeg + kc;
    Cout = C + (size_t)chunk * M * N;
  }
  const int MB = M >> 7;
  const int cM = MB >> 3;
  const int xcd = flat & 7, idxr = flat >> 3;
  const int byi = xcd * cM + (idxr % cM);      // A panel: XCD-resident slab
  const int bxi = idxr / cM;                   // B panel: streamed (L3)
  const int bm = byi * 128, bn = bxi * 128;
  const int t = threadIdx.x;
  const int lane = t & 63;
  const int wid = t >> 6;
  const int wr = wid >> 1, wc = wid & 1;
  const int fr = lane & 31;
  const int kg = lane >> 5;
  const int ub0 = wid * 128;
  const int Ksteps = K >> 5;

  f32x16 acc[2][2];
  #pragma unroll
  for (int mi = 0; mi < 2; ++mi)
    #pragma unroll
    for (int ni = 0; ni < 2; ++ni)
      #pragma unroll
      for (int r = 0; r < 16; ++r) acc[mi][ni][r] = 0.f;

  for (int k0 = kbeg; k0 < kend; k0 += 32) {
    const int ks = k0 >> 5;
    const size_t tB = ((size_t)(bxi * Ksteps + ks)) << 12;
    if (Af) {
      #pragma unroll
      for (int r = 0; r < 2; ++r) {
        int u = t + 256 * r;
        int row = u >> 2, ch = u & 3;
        const float* s0 = Af + (size_t)(bm + row) * K + k0 + ch * 8;
        float4 v0 = *(const float4*)s0, v1 = *(const float4*)(s0 + 4);
        float f[8] = {v0.x,v0.y,v0.z,v0.w,v1.x,v1.y,v1.z,v1.w};
        union { ushort u16[8]; uint4 q; } Hh, Ll;
        #pragma unroll
        for (int j = 0; j < 8; ++j) {
          ushort hh = f2bf(f[j]);
          Hh.u16[j] = hh; Ll.u16[j] = f2bf(f[j] - bf2f(hh));
        }
        *(uint4*)&sAh[ch * 1024 + row * 8] = Hh.q;
        *(uint4*)&sAl[ch * 1024 + row * 8] = Ll.q;
      }
    } else {
      const size_t tA = ((size_t)(byi * Ksteps + ks)) << 12;
      const ushort* a0 = Ah + tA;
      const ushort* a1 = Al + tA;
      gload16(a0 + (size_t)(ub0 + lane) * 8,      sAh + ub0 * 8);
      gload16(a0 + (size_t)(ub0 + 64 + lane) * 8, sAh + (ub0 + 64) * 8);
      gload16(a1 + (size_t)(ub0 + lane) * 8,      sAl + ub0 * 8);
      gload16(a1 + (size_t)(ub0 + 64 + lane) * 8, sAl + (ub0 + 64) * 8);
    }
    {
      const ushort* b0 = Bh + tB;
      const ushort* b1 = Bl + tB;
      gload16(b0 + (size_t)(ub0 + lane) * 8,      sBh + ub0 * 8);
      gload16(b0 + (size_t)(ub0 + 64 + lane) * 8, sBh + (ub0 + 64) * 8);
      gload16(b1 + (size_t)(ub0 + lane) * 8,      sBl + ub0 * 8);
      gload16(b1 + (size_t)(ub0 + 64 + lane) * 8, sBl + (ub0 + 64) * 8);
    }
    __syncthreads();
    #pragma unroll
    for (int ksl = 0; ksl < 2; ++ksl) {
      const int co = (ksl * 2 + kg) * 1024;
      bf16x8 ah[2], al[2], bh[2], bl[2];
      #pragma unroll
      for (int mi = 0; mi < 2; ++mi) {
        ah[mi] = *(const bf16x8*)&sAh[co + (wr * 64 + mi * 32 + fr) * 8];
        al[mi] = *(const bf16x8*)&sAl[co + (wr * 64 + mi * 32 + fr) * 8];
        bh[mi] = *(const bf16x8*)&sBh[co + (wc * 64 + mi * 32 + fr) * 8];
        bl[mi] = *(const bf16x8*)&sBl[co + (wc * 64 + mi * 32 + fr) * 8];
      }
      #pragma unroll
      for (int mi = 0; mi < 2; ++mi)
        #pragma unroll
        for (int ni = 0; ni < 2; ++ni) {
          acc[mi][ni] = __builtin_amdgcn_mfma_f32_32x32x16_bf16(ah[mi], bh[ni], acc[mi][ni], 0, 0, 0);
          acc[mi][ni] = __builtin_amdgcn_mfma_f32_32x32x16_bf16(ah[mi], bl[ni], acc[mi][ni], 0, 0, 0);
          acc[mi][ni] = __builtin_amdgcn_mfma_f32_32x32x16_bf16(al[mi], bh[ni], acc[mi][ni], 0, 0, 0);
        }
    }
    __syncthreads();
  }
  #pragma unroll
  for (int mi = 0; mi < 2; ++mi) {
    #pragma unroll
    for (int ni = 0; ni < 2; ++ni) {
      #pragma unroll
      for (int r = 0; r < 16; ++r) {
        int row = bm + wr * 64 + mi * 32 + (r & 3) + 8 * (r >> 2) + 4 * kg;
        int col = bn + wc * 64 + ni * 32 + fr;
        float v = acc[mi][ni][r];
        size_t idx;
        if (epi == 3) {
          int mtx = col >> 11, cc = col & 2047;
          idx = ((size_t)mtx * M + row) * 2048 + cc;
        } else {
          idx = (size_t)row * N + col;
          if (split < 2) {
            if (epi == 1) v += X[idx];
            else if (epi == 2) { float g = X[idx]; v = (g / (1.f + expf(-g))) * v; }
          }
        }
        Cout[idx] = v;
      }
    }
  }
}

// ---------------- FFN GEMM: bf16x2, BK=64 (drain-amortized, benched r16) ----------------
__global__ __launch_bounds__(256) void gemm_ffn64(
    const ushort* __restrict__ Ah, const ushort* __restrict__ Al,
    const float* __restrict__ Af,
    const ushort* __restrict__ Bh,
    float* __restrict__ C, const float* __restrict__ X,
    int M, int N, int K, int epi, int split)
{
  __shared__ __align__(16) ushort sAh[8192];
  __shared__ __align__(16) ushort sAl[8192];
  __shared__ __align__(16) ushort sBh[8192];
  int flat = blockIdx.x;
  int kbeg = 0, kend = K;
  float* Cout = C;
  if (split >= 2) {
    int nb = gridDim.x / split;
    int chunk = flat / nb;
    flat -= chunk * nb;
    int kc = K / split;
    kbeg = chunk * kc; kend = kbeg + kc;
    Cout = C + (size_t)chunk * M * N;
  }
  const int MB = M >> 7;
  const int cM = MB >> 3;
  const int xcd = flat & 7, idxr = flat >> 3;
  const int byi = xcd * cM + (idxr % cM);      // A panel: XCD-resident slab
  const int bxi = idxr / cM;                   // B panel: streamed (L3)
  const int bm = byi * 128, bn = bxi * 128;
  const int t = threadIdx.x;
  const int lane = t & 63;
  const int wid = t >> 6;
  const int wr = wid >> 1, wc = wid & 1;
  const int fr = lane & 31;
  const int kg = lane >> 5;
  const int ub2 = wid * 256;                   // 1024 idx-units per 2-tile pair
  const int Ksteps = K >> 5;                   // 32-k tile units

  f32x16 acc[2][2];
  #pragma unroll
  for (int mi = 0; mi < 2; ++mi)
    #pragma unroll
    for (int ni = 0; ni < 2; ++ni)
      #pragma unroll
      for (int r = 0; r < 16; ++r) acc[mi][ni][r] = 0.f;

  for (int k0 = kbeg; k0 < kend; k0 += 64) {
    const int ks = k0 >> 5;                    // first of 2 consecutive tiles
    const size_t tB = ((size_t)(bxi * Ksteps + ks)) << 12;
    if (Af) {
      #pragma unroll
      for (int r = 0; r < 4; ++r) {
        int u = t + 256 * r;                   // 0..1023
        int row = u >> 3, ch = u & 7;          // 8 chunks of 8 cols
        const float* s0 = Af + (size_t)(bm + row) * K + k0 + ch * 8;
        float4 v0 = *(const float4*)s0, v1 = *(const float4*)(s0 + 4);
        float f[8] = {v0.x,v0.y,v0.z,v0.w,v1.x,v1.y,v1.z,v1.w};
        union { ushort u16[8]; uint4 q; } Hh, Ll;
        #pragma unroll
        for (int j = 0; j < 8; ++j) {
          ushort hh = f2bf(f[j]);
          Hh.u16[j] = hh; Ll.u16[j] = f2bf(f[j] - bf2f(hh));
        }
        int dst = (ch >> 2) * 4096 + (ch & 3) * 1024 + row * 8;
        *(uint4*)&sAh[dst] = Hh.q;
        *(uint4*)&sAl[dst] = Ll.q;
      }
    } else {
      const size_t tA = ((size_t)(byi * Ksteps + ks)) << 12;
      const ushort* a0 = Ah + tA;
      const ushort* a1 = Al + tA;
      #pragma unroll
      for (int r = 0; r < 4; ++r) {
        gload16(a0 + (size_t)(ub2 + r * 64 + lane) * 8, sAh + (ub2 + r * 64) * 8);
        gload16(a1 + (size_t)(ub2 + r * 64 + lane) * 8, sAl + (ub2 + r * 64) * 8);
      }
    }
    {
      const ushort* b0 = Bh + tB;
      #pragma unroll
      for (int r = 0; r < 4; ++r)
        gload16(b0 + (size_t)(ub2 + r * 64 + lane) * 8, sBh + (ub2 + r * 64) * 8);
    }
    __syncthreads();
    #pragma unroll
    for (int ksl = 0; ksl < 4; ++ksl) {
      const int co = (ksl >> 1) * 4096 + (((ksl & 1) * 2 + kg)) * 1024;
      bf16x8 ah[2], al[2], bh[2];
      #pragma unroll
      for (int mi = 0; mi < 2; ++mi) {
        ah[mi] = *(const bf16x8*)&sAh[co + (wr * 64 + mi * 32 + fr) * 8];
        al[mi] = *(const bf16x8*)&sAl[co + (wr * 64 + mi * 32 + fr) * 8];
        bh[mi] = *(const bf16x8*)&sBh[co + (wc * 64 + mi * 32 + fr) * 8];
      }
      __builtin_amdgcn_s_setprio(1);
      #pragma unroll
      for (int mi = 0; mi < 2; ++mi)
        #pragma unroll
        for (int ni = 0; ni < 2; ++ni) {
          acc[mi][ni] = __builtin_amdgcn_mfma_f32_32x32x16_bf16(ah[mi], bh[ni], acc[mi][ni], 0, 0, 0);
          acc[mi][ni] = __builtin_amdgcn_mfma_f32_32x32x16_bf16(al[mi], bh[ni], acc[mi][ni], 0, 0, 0);
        }
      __builtin_amdgcn_s_setprio(0);
    }
    __syncthreads();
  }
  #pragma unroll
  for (int mi = 0; mi < 2; ++mi) {
    #pragma unroll
    for (int ni = 0; ni < 2; ++ni) {
      #pragma unroll
      for (int r = 0; r < 16; ++r) {
        int row = bm + wr * 64 + mi * 32 + (r & 3) + 8 * (r >> 2) + 4 * kg;
        int col = bn + wc * 64 + ni * 32 + fr;
        float v = acc[mi][ni][r];
        size_t idx = (size_t)row * N + col;
        if (split < 2) {
          if (epi == 1) v += X[idx];
          else if (epi == 2) { float g = X[idx]; v = (g / (1.f + expf(-g))) * v; }
        }
        Cout[idx] = v;
      }
    }
  }
}

// ---------------- o = sum(parts[0..np)) + x (split-K reduce + residual) ----------------
__global__ __launch_bounds__(256) void reduce_n(
    const float* __restrict__ parts, const float* __restrict__ x,
    float* __restrict__ o, int np)
{
  int g = blockIdx.x * 256 + threadIdx.x;     // NQ*H/4 float4
  float4 vx = ((const float4*)x)[g];
  float4 vo = vx;
  for (int p = 0; p < np; ++p) {
    float4 vp = ((const float4*)(parts + (size_t)p * NQ_ * H_))[g];
    vo.x += vp.x; vo.y += vp.y; vo.z += vp.z; vo.w += vp.w;
  }
  ((float4*)o)[g] = vo;
}

// ---------------- RoPE in-place on q and k ----------------
__global__ __launch_bounds__(256) void rope_k(
    float* __restrict__ qb, float* __restrict__ kb, const int* __restrict__ q_pos)
{
  int gid = blockIdx.x * 256 + threadIdx.x;   // NQ*NH*64
  int d = gid & 63;
  int h = (gid >> 6) & 15;
  int i = gid >> 10;
  int p = q_pos[i];
  double ang = (double)p * exp((double)d * -0.14391156831212787);
  float c = (float)cos(ang), s = (float)sin(ang);
  size_t ia = (size_t)i * H_ + h * HD_ + d;
  size_t ib = ia + 64;
  float qa = qb[ia], qbv = qb[ib];
  qb[ia] = qa * c - qbv * s;
  qb[ib] = qbv * c + qa * s;
  float ka = kb[ia], kbv = kb[ib];
  kb[ia] = ka * c - kbv * s;
  kb[ib] = kbv * c + ka * s;
}

// ---------------- K (hi only) + V^T (hi) bf16 planes ----------------
// kh: [NH][NK][HD]; vth: TILE-MAJOR [NH][NK/64][HD][64].  grid = (NK/64, NH)
// K-lo plane dropped (flash bt2: err = kl*q ~2^-9 of logit, validated r15/r16
// headroom — absmax floor is data-specific, pinned at 0.03125 since f32 build).
__global__ __launch_bounds__(256) void fill_kv_planes(
    const float* __restrict__ kcache, const float* __restrict__ vcache,
    const float* __restrict__ kb, const float* __restrict__ vb,
    const int* __restrict__ kv_idxs,
    ushort* __restrict__ kh, ushort* __restrict__ vth)
{
  __shared__ float vt[64][133];
  const int h = blockIdx.y;
  const int kbase = blockIdx.x * 64;
  const int t = threadIdx.x;
  #pragma unroll
  for (int r = 0; r < 8; ++r) {
    int idx = t + 256 * r;                     // 2048 float4
    int key = idx >> 5, d4 = idx & 31;
    int j = kbase + key;
    float4 kv, vv;
    if (j < NKV) {
      int tok = kv_idxs[j];
      size_t src = ((size_t)h * S_ + tok) * 32 + d4;
      kv = ((const float4*)kcache)[src];
      vv = ((const float4*)vcache)[src];
    } else {
      int i = j - NKV;
      size_t src = (size_t)i * 512 + h * 32 + d4;
      kv = ((const float4*)kb)[src];
      vv = ((const float4*)vb)[src];
    }
    ushort4 hh;
    hh.x = f2bf(kv.x); hh.y = f2bf(kv.y); hh.z = f2bf(kv.z); hh.w = f2bf(kv.w);
    size_t dst = ((size_t)(h * NK_ + j)) * 128 + d4 * 4;
    *(ushort4*)(kh + dst) = hh;
    vt[key][d4 * 4 + 0] = vv.x; vt[key][d4 * 4 + 1] = vv.y;
    vt[key][d4 * 4 + 2] = vv.z; vt[key][d4 * 4 + 3] = vv.w;
  }
  __syncthreads();
  #pragma unroll
  for (int r = 0; r < 8; ++r) {
    int idx = t + 256 * r;                     // 2048 groups of 4 keys
    int d = idx >> 4, kq = (idx & 15) * 4;
    float v0 = vt[kq + 0][d], v1 = vt[kq + 1][d], v2 = vt[kq + 2][d], v3 = vt[kq + 3][d];
    ushort4 hh;
    hh.x = f2bf(v0); hh.y = f2bf(v1); hh.z = f2bf(v2); hh.w = f2bf(v3);
    size_t dst = (((size_t)h * 64 + blockIdx.x) * 128 + d) * 64 + kq;
    *(ushort4*)(vth + dst) = hh;
  }
}

// ---------------- MFMA flash attention (4-way key-split, grid 1024, LPT order) ----------------
// bt2 QK: S = kh*(qh+ql) = kh*q  (drops kl*q, ~2^-9 of logit). Halves K-frag
// loads (8/chunk) and cuts QK MFMA 24->16 — shortens the serial latency chain.
struct MergeLDS4 { float buf[2][32][132]; float ml[2][2][32]; };

__global__ __launch_bounds__(256, 2) void flash_mfma(
    const float* __restrict__ qb, const ushort* __restrict__ khg,
    const ushort* __restrict__ vthg,
    const int* __restrict__ q_pos, const int* __restrict__ k_pos,
    ushort* __restrict__ ctxh, ushort* __restrict__ ctxl)
{
  __shared__ MergeLDS4 U;
  const int b = blockIdx.x;
  const int h = (b & 7) * 2 + ((b >> 3) & 1);  // 2 heads per XCD slab
  const int qb32 = 63 - (b >> 4);              // heaviest blocks first (LPT)
  const int q0 = qb32 * 32;
  const int t = threadIdx.x;
  const int wk = t >> 6, lane = t & 63;
  const int kg = lane >> 5;
  const int qc = lane & 31;
  const int qi = q0 + qc;
  const float scale = 0.08838834764831844f;    // 1/sqrt(128)

  bf16x8 qh[8], ql[8];
  {
    const float4* q4 = (const float4*)qb;
    #pragma unroll
    for (int s = 0; s < 8; ++s) {
      size_t a = (size_t)qi * 512 + h * 32 + s * 4 + kg * 2;
      float4 f0 = q4[a], f1 = q4[a + 1];
      float f[8] = {f0.x, f0.y, f0.z, f0.w, f1.x, f1.y, f1.z, f1.w};
      union { ushort u[8]; bf16x8 v; } Hq, Lq;
      #pragma unroll
      for (int j = 0; j < 8; ++j) {
        float qs = f[j] * scale;
        ushort hh = f2bf(qs);
        Hq.u[j] = hh; Lq.u[j] = f2bf(qs - bf2f(hh));
      }
      qh[s] = Hq.v; ql[s] = Lq.v;
    }
  }
  const int qp = q_pos[qi];
  const int wave_qmin = __shfl(qp, 0);
  const int wave_qmax = __shfl(qp, 31);       // q ascend within 32-block

  const ushort* kh_base = khg + (size_t)h * NK_ * 128;
  const ushort* vt_base = vthg + (size_t)h * NK_ * 128;   // [NK/64][128][64]

  f32x16 acc[4];
  #pragma unroll
  for (int f = 0; f < 4; ++f)
    #pragma unroll
    for (int r = 0; r < 16; ++r) acc[f][r] = 0.f;
  float m_run = -INFINITY, l_run = 0.f;

  for (int c = wk; c < NK_ / 32; c += 4) {     // interleaved 32-key chunks
    const int krow0 = c * 32;
    const int kpv = k_pos[krow0 + qc];
    if (__shfl(kpv, 0) > wave_qmax) continue;  // chunk fully masked
    const bool needmask = (__shfl(kpv, 31) > wave_qmin);

    f32x16 sA, sB;
    #pragma unroll
    for (int r = 0; r < 16; ++r) { sA[r] = 0.f; sB[r] = 0.f; }
    const ushort* krow = kh_base + (size_t)(krow0 + qc) * 128 + kg * 8;
    __builtin_amdgcn_s_setprio(1);
    #pragma unroll
    for (int s = 0; s < 8; ++s) {
      bf16x8 khf = *(const bf16x8*)(krow + s * 16);
      sA = __builtin_amdgcn_mfma_f32_32x32x16_bf16(khf, qh[s], sA, 0, 0, 0);
      sB = __builtin_amdgcn_mfma_f32_32x32x16_bf16(khf, ql[s], sB, 0, 0, 0);
    }
    __builtin_amdgcn_s_setprio(0);
    // V fragments from tile-major layout (issued early, hide under softmax)
    bf16x8 vf[2][4];
    {
      const ushort* vtile = vt_base + (size_t)(c >> 1) * 8192;   // 128*64
      #pragma unroll
      for (int ks = 0; ks < 2; ++ks) {
        const int kc = (c & 1) * 32 + ks * 16 + kg * 8;          // within-tile key
        #pragma unroll
        for (int f = 0; f < 4; ++f)
          vf[ks][f] = *(const bf16x8*)(vtile + (f * 32 + qc) * 64 + kc);
      }
    }
    float sc[16];
    #pragma unroll
    for (int r = 0; r < 16; ++r) sc[r] = sA[r] + sB[r];
    if (needmask) {
      #pragma unroll
      for (int r = 0; r < 16; ++r) {
        int crow = (r & 3) + 8 * (r >> 2) + 4 * kg;
        sc[r] = (__shfl(kpv, crow) <= qp) ? sc[r] : -INFINITY;
      }
    }
    float mloc = sc[0];
    #pragma unroll
    for (int r = 1; r < 16; ++r) mloc = fmaxf(mloc, sc[r]);
    mloc = fmaxf(mloc, __shfl_xor(mloc, 32));
    float m_new = fmaxf(m_run, mloc);
    float mexp = (m_new == -INFINITY) ? 0.f : m_new;
    if (__any(m_new > m_run)) {
      float aa = __expf(m_run - mexp);
      l_run *= aa;
      #pragma unroll
      for (int f = 0; f < 4; ++f)
        #pragma unroll
        for (int r = 0; r < 16; ++r) acc[f][r] *= aa;
    }
    m_run = m_new;
    float p[16]; float psum = 0.f;
    #pragma unroll
    for (int r = 0; r < 16; ++r) { p[r] = __expf(sc[r] - mexp); psum += p[r]; }
    psum += __shfl_xor(psum, 32);
    l_run += psum;
    bf16x8 pfh[2], pfl[2];
    #pragma unroll
    for (int sl = 0; sl < 2; ++sl) {
      const float* pp = p + sl * 8;
      unsigned a0 = cvt_pk_bf16(pp[0], pp[1]);
      unsigned a1 = cvt_pk_bf16(pp[2], pp[3]);
      unsigned b0 = cvt_pk_bf16(pp[4], pp[5]);
      unsigned b1 = cvt_pk_bf16(pp[6], pp[7]);
      unsigned a0x = (unsigned)__shfl_xor((int)a0, 32);
      unsigned a1x = (unsigned)__shfl_xor((int)a1, 32);
      unsigned b0x = (unsigned)__shfl_xor((int)b0, 32);
      unsigned b1x = (unsigned)__shfl_xor((int)b1, 32);
      union { unsigned wd[4]; bf16x8 v; } PH, PL;
      PH.wd[0] = kg ? b0x : a0;
      PH.wd[1] = kg ? b1x : a1;
      PH.wd[2] = kg ? b0 : a0x;
      PH.wd[3] = kg ? b1 : a1x;
      float r0 = pp[0] - bflo(a0), r1 = pp[1] - bfhi(a0);
      float r2 = pp[2] - bflo(a1), r3 = pp[3] - bfhi(a1);
      float r4 = pp[4] - bflo(b0), r5 = pp[5] - bfhi(b0);
      float r6 = pp[6] - bflo(b1), r7 = pp[7] - bfhi(b1);
      unsigned c0 = cvt_pk_bf16(r0, r1);
      unsigned c1 = cvt_pk_bf16(r2, r3);
      unsigned d0 = cvt_pk_bf16(r4, r5);
      unsigned d1 = cvt_pk_bf16(r6, r7);
      unsigned c0x = (unsigned)__shfl_xor((int)c0, 32);
      unsigned c1x = (unsigned)__shfl_xor((int)c1, 32);
      unsigned d0x = (unsigned)__shfl_xor((int)d0, 32);
      unsigned d1x = (unsigned)__shfl_xor((int)d1, 32);
      PL.wd[0] = kg ? d0x : c0;
      PL.wd[1] = kg ? d1x : c1;
      PL.wd[2] = kg ? d0 : c0x;
      PL.wd[3] = kg ? d1 : c1x;
      pfh[sl] = PH.v; pfl[sl] = PL.v;
    }
    __builtin_amdgcn_s_setprio(1);
    #pragma unroll
    for (int ks = 0; ks < 2; ++ks) {
      acc[0] = __builtin_amdgcn_mfma_f32_32x32x16_bf16(vf[ks][0], pfh[ks], acc[0], 0, 0, 0);
      acc[1] = __builtin_amdgcn_mfma_f32_32x32x16_bf16(vf[ks][1], pfh[ks], acc[1], 0, 0, 0);
      acc[2] = __builtin_amdgcn_mfma_f32_32x32x16_bf16(vf[ks][2], pfh[ks], acc[2], 0, 0, 0);
      acc[3] = __builtin_amdgcn_mfma_f32_32x32x16_bf16(vf[ks][3], pfh[ks], acc[3], 0, 0, 0);
      acc[0] = __builtin_amdgcn_mfma_f32_32x32x16_bf16(vf[ks][0], pfl[ks], acc[0], 0, 0, 0);
      acc[1] = __builtin_amdgcn_mfma_f32_32x32x16_bf16(vf[ks][1], pfl[ks], acc[1], 0, 0, 0);
      acc[2] = __builtin_amdgcn_mfma_f32_32x32x16_bf16(vf[ks][2], pfl[ks], acc[2], 0, 0, 0);
      acc[3] = __builtin_amdgcn_mfma_f32_32x32x16_bf16(vf[ks][3], pfl[ks], acc[3], 0, 0, 0);
    }
    __builtin_amdgcn_s_setprio(0);
  }

  // ---- 2-stage 4-way merge (guarded online-softmax combine) ----
  if (wk >= 2) {
    const int slot = wk - 2;
    #pragma unroll
    for (int f = 0; f < 4; ++f)
      #pragma unroll
      for (int r = 0; r < 16; ++r) {
        int d = f * 32 + (r & 3) + 8 * (r >> 2) + 4 * kg;
        U.buf[slot][qc][d] = acc[f][r];
      }
    if (kg == 0) { U.ml[slot][0][qc] = m_run; U.ml[slot][1][qc] = l_run; }
  }
  __syncthreads();
  if (wk < 2) {
    const int slot = wk;
    float m2 = U.ml[slot][0][qc];
    float l2 = U.ml[slot][1][qc];
    float mm = fmaxf(m_run, m2);
    float me = (mm == -INFINITY) ? 0.f : mm;
    float a1 = __expf(m_run - me);
    float a2 = __expf(m2 - me);
    #pragma unroll
    for (int f = 0; f < 4; ++f)
      #pragma unroll
      for (int r = 0; r < 16; ++r) {
        int d = f * 32 + (r & 3) + 8 * (r >> 2) + 4 * kg;
        acc[f][r] = acc[f][r] * a1 + U.buf[slot][qc][d] * a2;
      }
    m_run = mm; l_run = l_run * a1 + l2 * a2;
  }
  __syncthreads();
  if (wk == 1) {
    #pragma unroll
    for (int f = 0; f < 4; ++f)
      #pragma unroll
      for (int r = 0; r < 16; ++r) {
        int d = f * 32 + (r & 3) + 8 * (r >> 2) + 4 * kg;
        U.buf[0][qc][d] = acc[f][r];
      }
    if (kg == 0) { U.ml[0][0][qc] = m_run; U.ml[0][1][qc] = l_run; }
  }
  __syncthreads();
  if (wk == 0) {
    float m2 = U.ml[0][0][qc];
    float l2 = U.ml[0][1][qc];
    float mm = fmaxf(m_run, m2);
    float me = (mm == -INFINITY) ? 0.f : mm;
    float a1 = __expf(m_run - me);
    float a2 = __expf(m2 - me);
    float lt = l_run * a1 + l2 * a2;
    float inv = 1.f / lt;
    #pragma unroll
    for (int f = 0; f < 4; ++f)
      #pragma unroll
      for (int rq = 0; rq < 4; ++rq) {
        float o[4];
        #pragma unroll
        for (int j = 0; j < 4; ++j) {
          int d = f * 32 + j + 8 * rq + 4 * kg;
          o[j] = (acc[f][rq * 4 + j] * a1 + U.buf[0][qc][d] * a2) * inv;
        }
        ushort4 hh, ll;
        hh.x = f2bf(o[0]); ll.x = f2bf(o[0] - bf2f(hh.x));
        hh.y = f2bf(o[1]); ll.y = f2bf(o[1] - bf2f(hh.y));
        hh.z = f2bf(o[2]); ll.z = f2bf(o[2] - bf2f(hh.z));
        hh.w = f2bf(o[3]); ll.w = f2bf(o[3] - bf2f(hh.w));
        int d = h * 128 + f * 32 + kg * 4 + rq * 8;
        size_t oidx = tileoff(qi, d, H_);
        *(ushort4*)(ctxh + oidx) = hh;
        *(ushort4*)(ctxl + oidx) = ll;
      }
  }
}

// ---------------- cache scatter outputs ----------------
__global__ __launch_bounds__(256) void write_kv(
    const float* __restrict__ kcache, const float* __restrict__ vcache,
    const float* __restrict__ kb, const float* __restrict__ vb,
    const int* __restrict__ in_hs, const int* __restrict__ map_full,
    float* __restrict__ kc_o, float* __restrict__ vc_o)
{
  int gid = blockIdx.x * 256 + threadIdx.x;   // NH*S*HD/4
  int d4 = gid & 31;
  int s  = (gid >> 5) & (S_ - 1);
  int h  = gid >> 17;
  float4 kv, vv;
  if (in_hs[s]) {
    int i = map_full[s];
    size_t src = (size_t)i * (H_ / 4) + h * 32 + d4;
    kv = ((const float4*)kb)[src];
    vv = ((const float4*)vb)[src];
  } else {
    kv = ((const float4*)kcache)[gid];
    vv = ((const float4*)vcache)[gid];
  }
  ((float4*)kc_o)[gid] = kv;
  ((float4*)vc_o)[gid] = vv;
}

__global__ __launch_bounds__(256) void aux_write(
    const float* __restrict__ outb, const float* __restrict__ auxc,
    const int* __restrict__ pruned_bit, const int* __restrict__ aux_bit,
    const int* __restrict__ map_full, float* __restrict__ aux_o)
{
  int gid = blockIdx.x * 256 + threadIdx.x;   // S*H/4
  int c4 = gid & 511;
  int s  = gid >> 9;
  float4 v;
  if (pruned_bit[s] && !aux_bit[s])
    v = ((const float4*)outb)[(size_t)map_full[s] * 512 + c4];
  else
    v = ((const float4*)auxc)[gid];
  ((float4*)aux_o)[gid] = v;
}

// ---------------- host ----------------
extern "C" void kernel_launch(void* const* d_in, const int* in_sizes, int n_in,
                              void* d_out, int out_size, void* d_ws, size_t ws_size,
                              hipStream_t stream) {
  (void)in_sizes; (void)n_in; (void)out_size; (void)ws_size;
  const float* hidden  = (const float*)d_in[0];
  const float* kcache  = (const float*)d_in[1];
  const float* vcache  = (const float*)d_in[2];
  const float* auxc    = (const float*)d_in[3];
  const int* kv_idxs   = (const int*)d_in[4];
  const int* aux_idxs  = (const int*)d_in[5];
  const int* new_idxs  = (const int*)d_in[6];
  const int* positions = (const int*)d_in[7];
  const float* wq      = (const float*)d_in[8];
  const float* wk      = (const float*)d_in[9];
  const float* wv      = (const float*)d_in[10];
  const float* wo      = (const float*)d_in[11];
  const float* w_gate  = (const float*)d_in[12];
  const float* w_up    = (const float*)d_in[13];
  const float* w_down  = (const float*)d_in[14];
  const float* ln1     = (const float*)d_in[15];
  const float* ln2     = (const float*)d_in[16];

  float* out_o = (float*)d_out;
  float* kc_o  = out_o + (size_t)NQ_ * H_;
  float* vc_o  = kc_o + (size_t)NH_ * S_ * HD_;
  float* aux_o = vc_o + (size_t)NH_ * S_ * HD_;

  // workspace (units of M4 = 4M floats = 16.78 MB), 11 slots + ints.
  // wo split-K=4: partials -> slots 2,3,4,5 (qb/kb/vb/khp dead after flash/write_kv)
  // down split-K=2: partials -> slots 0,1 (hs, x-planes dead by then)
  // klp slot (6) now unused in attn phase (flash bt2).
  float* W = (float*)d_ws;
  const size_t M4 = 4194304;                  // NQ*H
  float* hs    = W;
  ushort* xh   = (ushort*)(W + 1 * M4);
  ushort* xl   = xh + (size_t)NQ_ * H_;
  float* qb    = W + 2 * M4;
  float* kb    = W + 3 * M4;
  float* vb    = W + 4 * M4;
  ushort* bt3_h = (ushort*)(W + 5 * M4);      // 3*H*H ushorts (slots 5-6, QKV phase)
  ushort* bt3_l = (ushort*)(W + 8 * M4);      // slots 8-9 (QKV phase only)
  ushort* khp  = (ushort*)(W + 5 * M4);
  ushort* vthp = (ushort*)(W + 7 * M4);
  ushort* ctxh = (ushort*)(W + 8 * M4);
  ushort* ctxl = ctxh + (size_t)NQ_ * H_;
  ushort* bt_h = (ushort*)(W + 9 * M4);
  ushort* bt_l = bt_h + (size_t)H_ * H_;
  float* hs2   = W + 10 * M4;
  float* act   = W + 2 * M4;                  // slots 2-5 (FFN phase)
  ushort* btg_h = (ushort*)(W + 6 * M4);      // slots 6-7
  ushort* btg_l = (ushort*)(W + 8 * M4);      // slots 8-9
  float* wo_p  = W + 2 * M4;                  // wo split-4 partials (slots 2-5)
  float* dn_p  = W + 0 * M4;                  // down split-2 partials (slots 0-1)
  int* ip = (int*)(W + 11 * M4);
  int* hs_idxs = ip;           ip += NQ_;
  int* q_pos   = ip;           ip += NQ_;
  int* key_tok = ip;           ip += NK_;
  int* k_pos   = ip;           ip += NK_;
  int* map_full= ip;           ip += S_;
  int* in_hs   = ip;           ip += S_;
  int* aux_bit = ip;           ip += S_;
  int* pruned  = ip;           ip += S_;
  int* last_hs = ip;           ip += 4;

  prep_build<<<16, 256, 0, stream>>>(kv_idxs, aux_idxs, new_idxs, positions,
      hs_idxs, q_pos, key_tok, k_pos, map_full, in_hs, aux_bit, pruned, last_hs);
  prep_scatter<<<10, 256, 0, stream>>>(hs_idxs, aux_idxs, map_full, in_hs, aux_bit);
  prune_set<<<2, 256, 0, stream>>>(kv_idxs, pruned);
  build_hs<<<4096, 256, 0, stream>>>(hidden, auxc, aux_idxs, hs);
  rmsnorm_split<<<NQ_, 256, 0, stream>>>(hs, ln1, xh, xl);

  const dim3 gTH(H_ / 64, H_ / 64);
  // QKV fused: B = concat(wq,wk,wv) panels, N = 6144, epi 3 de-concats C. (bf16x3)
  wsplit_t<<<gTH, 256, 0, stream>>>(wq, bt3_h,                      bt3_l,                      H_, H_, H_);
  wsplit_t<<<gTH, 256, 0, stream>>>(wk, bt3_h + (size_t)H_ * H_,    bt3_l + (size_t)H_ * H_,    H_, H_, H_);
  wsplit_t<<<gTH, 256, 0, stream>>>(wv, bt3_h + (size_t)2 * H_ * H_, bt3_l + (size_t)2 * H_ * H_, H_, H_, H_);
  gemm_mfma<<<768, 256, 0, stream>>>(xh, xl, nullptr, bt3_h, bt3_l, qb, nullptr, NQ_, 3 * H_, H_, 3, 0);

  rope_k<<<8192, 256, 0, stream>>>(qb, kb, q_pos);
  fill_kv_planes<<<dim3(64, 16), 256, 0, stream>>>(kcache, vcache, kb, vb, kv_idxs,
      khp, vthp);

  flash_mfma<<<1024, 256, 0, stream>>>(qb, khp, vthp, q_pos, k_pos, ctxh, ctxl);
  write_kv<<<8192, 256, 0, stream>>>(kcache, vcache, kb, vb, in_hs, map_full, kc_o, vc_o);

  // wo GEMM: split-K=4 (grid 1024), bf16x3, partials in slots 2-5, residual-add
  wsplit_t<<<gTH, 256, 0, stream>>>(wo, bt_h, bt_l, H_, H_, H_);
  gemm_mfma<<<1024, 256, 0, stream>>>(ctxh, ctxl, nullptr, bt_h, bt_l, wo_p, nullptr, NQ_, H_, H_, 0, 4);
  reduce_n<<<4096, 256, 0, stream>>>(wo_p, hs, hs2, 4);
  rmsnorm_split<<<NQ_, 256, 0, stream>>>(hs2, ln2, xh, xl);

  // FFN GEMMs: bf16x2, BK=64 (drain-amortized)
  wsplit_t<<<dim3(FF_ / 64, H_ / 64), 256, 0, stream>>>(w_gate, btg_h, btg_l, H_, FF_, FF_);
  gemm_ffn64<<<1024, 256, 0, stream>>>(xh, xl, nullptr, btg_h, act, nullptr, NQ_, FF_, H_, 0, 0);
  wsplit_t<<<dim3(FF_ / 64, H_ / 64), 256, 0, stream>>>(w_up, btg_h, btg_l, H_, FF_, FF_);
  gemm_ffn64<<<1024, 256, 0, stream>>>(xh, xl, nullptr, btg_h, act, act, NQ_, FF_, H_, 2, 0);
  // down GEMM: split-K=2 (grid 512), f32-A split path, BK=64, partials + residual
  wsplit_t<<<dim3(H_ / 64, FF_ / 64), 256, 0, stream>>>(w_down, btg_h, btg_l, FF_, H_, H_);
  gemm_ffn64<<<512, 256, 0, stream>>>(nullptr, nullptr, act, btg_h, dn_p, nullptr, NQ_, H_, FF_, 0, 2);
  reduce_n<<<4096, 256, 0, stream>>>(dn_p, hs2, out_o, 2);

  aux_write<<<8192, 256, 0, stream>>>(out_o, auxc, pruned, aux_bit, map_full, aux_o);
}

// Round 18
// 1029.434 us; speedup vs baseline: 1.2303x; 1.1021x over previous
//
#include <hip/hip_runtime.h>
#include <math.h>

// ---------------- problem constants ----------------
constexpr int S_    = 4096;
constexpr int NKV   = 2048;
constexpr int NAUX  = 512;
constexpr int NNEW  = 1536;
constexpr int H_    = 2048;
constexpr int NH_   = 16;
constexpr int HD_   = 128;
constexpr int FF_   = 8192;
constexpr int NQ_   = 2048;   // NNEW + NAUX
constexpr int NK_   = 4096;   // NKV + NQ
constexpr int PRUNE = 409;
constexpr float EPSF = 1e-6f;

typedef __attribute__((ext_vector_type(8))) short bf16x8;
typedef __attribute__((ext_vector_type(16))) float f32x16;

__device__ __forceinline__ ushort f2bf(float x) {
  union { float f; unsigned u; } a; a.f = x;
  unsigned r = a.u + 0x7fffu + ((a.u >> 16) & 1u);
  return (ushort)(r >> 16);
}
__device__ __forceinline__ float bf2f(ushort h) {
  union { unsigned u; float f; } a; a.u = ((unsigned)h) << 16;
  return a.f;
}
__device__ __forceinline__ unsigned cvt_pk_bf16(float a, float b) {
  unsigned r;
  asm("v_cvt_pk_bf16_f32 %0, %1, %2" : "=v"(r) : "v"(a), "v"(b));
  return r;
}
__device__ __forceinline__ float bflo(unsigned w) { union { unsigned u; float f; } x; x.u = w << 16; return x.f; }
__device__ __forceinline__ float bfhi(unsigned w) { union { unsigned u; float f; } x; x.u = w & 0xffff0000u; return x.f; }

// async global->LDS, 16B per lane. LDS dest = base + lane*16 (HW); global src per-lane.
__device__ __forceinline__ void gload16(const ushort* g, ushort* l) {
  __builtin_amdgcn_global_load_lds(
      (const __attribute__((address_space(1))) unsigned int*)g,
      (__attribute__((address_space(3))) unsigned int*)l, 16, 0, 0);
}

// tiled bf16-plane layout: [row>>7][k>>5][(k>>3)&3][row&127][k&7]
// each 128x32 tile = 8KB contiguous = the exact LDS staging image (chunk-major).
// consecutive k-step tiles of one panel are contiguous (16KB per BK=64 pair).
__device__ __forceinline__ size_t tileoff(int row, int k, int K) {
  return ((size_t)((row >> 7) * (K >> 5) + (k >> 5)) << 12)
       + (size_t)((((k >> 3) & 3) << 10) + ((row & 127) << 3) + (k & 7));
}

// ---------------- index prep ----------------
__global__ __launch_bounds__(256) void prep_build(
    const int* __restrict__ kv_idxs, const int* __restrict__ aux_idxs,
    const int* __restrict__ new_idxs, const int* __restrict__ positions,
    int* hs_idxs, int* q_pos, int* key_tok, int* k_pos,
    int* map_full, int* in_hs, int* aux_bit, int* pruned_bit, int* last_hs)
{
  int t = blockIdx.x * 256 + threadIdx.x;     // grid covers 4096
  if (t < S_) { map_full[t] = 0; in_hs[t] = 0; aux_bit[t] = 0; pruned_bit[t] = 0; }
  if (t < NQ_) {
    int tok = (t < NNEW) ? new_idxs[t] : aux_idxs[t - NNEW];
    hs_idxs[t] = tok;
    q_pos[t] = positions[tok];
  }
  if (t < NK_) {
    int tok;
    if (t < NKV) tok = kv_idxs[t];
    else { int i = t - NKV; tok = (i < NNEW) ? new_idxs[i] : aux_idxs[i - NNEW]; }
    key_tok[t] = tok;
    k_pos[t] = positions[tok];
  }
  if (t < NNEW && new_idxs[t] == S_ - 1) last_hs[0] = t;
}

__global__ __launch_bounds__(256) void prep_scatter(
    const int* __restrict__ hs_idxs, const int* __restrict__ aux_idxs,
    int* map_full, int* in_hs, int* aux_bit)
{
  int t = blockIdx.x * 256 + threadIdx.x;
  if (t < NQ_) { int tok = hs_idxs[t]; map_full[tok] = t; in_hs[tok] = 1; }
  else if (t < NQ_ + NAUX) { aux_bit[aux_idxs[t - NQ_]] = 1; }
}

// Prune semantics of the reference (bug-compatible): see previous session note.
__global__ __launch_bounds__(256) void prune_set(
    const int* __restrict__ kv_idxs, int* __restrict__ pruned_bit)
{
  int t = blockIdx.x * 256 + threadIdx.x;
  if (t < PRUNE - 1) pruned_bit[kv_idxs[t]] = 1;
  if (t == PRUNE - 1) pruned_bit[S_ - 1] = 1;
}

// ---------------- hs = concat(hidden_states, aux_cache[aux_idxs]) ----------------
__global__ __launch_bounds__(256) void build_hs(
    const float* __restrict__ hidden, const float* __restrict__ auxc,
    const int* __restrict__ aux_idxs, float* __restrict__ hs)
{
  int gid = blockIdx.x * 256 + threadIdx.x;   // NQ*H/4 float4
  int c4 = gid & 511;                          // H/4 = 512
  int i  = gid >> 9;
  const float4* src;
  if (i < NNEW) src = (const float4*)hidden + (size_t)i * 512 + c4;
  else          src = (const float4*)auxc + (size_t)aux_idxs[i - NNEW] * 512 + c4;
  ((float4*)hs)[gid] = *src;
}

// ---------------- rmsnorm -> tiled bf16 hi/lo planes ----------------
__global__ __launch_bounds__(256) void rmsnorm_split(
    const float* __restrict__ in, const float* __restrict__ w,
    ushort* __restrict__ oh, ushort* __restrict__ ol)
{
  int row = blockIdx.x, t = threadIdx.x;
  const float4* r4 = (const float4*)(in + (size_t)row * H_);
  const float4* w4 = (const float4*)w;
  float ss = 0.f;
  float4 v0 = r4[t], v1 = r4[t + 256];
  ss += v0.x*v0.x + v0.y*v0.y + v0.z*v0.z + v0.w*v0.w;
  ss += v1.x*v1.x + v1.y*v1.y + v1.z*v1.z + v1.w*v1.w;
  __shared__ float red[256];
  red[t] = ss; __syncthreads();
  for (int s = 128; s > 0; s >>= 1) { if (t < s) red[t] += red[t + s]; __syncthreads(); }
  float inv = rsqrtf(red[0] / (float)H_ + EPSF);
  float4 wv0 = w4[t], wv1 = w4[t + 256];
  float f[8];
  f[0] = v0.x*inv*wv0.x; f[1] = v0.y*inv*wv0.y; f[2] = v0.z*inv*wv0.z; f[3] = v0.w*inv*wv0.w;
  f[4] = v1.x*inv*wv1.x; f[5] = v1.y*inv*wv1.y; f[6] = v1.z*inv*wv1.z; f[7] = v1.w*inv*wv1.w;
  ushort4 h0, l0, h1, l1;
  h0.x = f2bf(f[0]); l0.x = f2bf(f[0] - bf2f(h0.x));
  h0.y = f2bf(f[1]); l0.y = f2bf(f[1] - bf2f(h0.y));
  h0.z = f2bf(f[2]); l0.z = f2bf(f[2] - bf2f(h0.z));
  h0.w = f2bf(f[3]); l0.w = f2bf(f[3] - bf2f(h0.w));
  h1.x = f2bf(f[4]); l1.x = f2bf(f[4] - bf2f(h1.x));
  h1.y = f2bf(f[5]); l1.y = f2bf(f[5] - bf2f(h1.y));
  h1.z = f2bf(f[6]); l1.z = f2bf(f[6] - bf2f(h1.z));
  h1.w = f2bf(f[7]); l1.w = f2bf(f[7] - bf2f(h1.w));
  size_t o0 = tileoff(row, t * 4, H_);
  size_t o1 = tileoff(row, 1024 + t * 4, H_);
  *(ushort4*)(oh + o0) = h0; *(ushort4*)(ol + o0) = l0;
  *(ushort4*)(oh + o1) = h1; *(ushort4*)(ol + o1) = l1;
}

// ---------------- weight transpose + bf16 hi/lo split (tiled output) ----------------
// W[K][.] f32 (row stride ld) -> Th (and Tl if non-null) tiled planes.
// grid = (N/64, K/64).
__global__ __launch_bounds__(256) void wsplit_t(
    const float* __restrict__ Wsrc, ushort* __restrict__ Th, ushort* __restrict__ Tl,
    int K, int N, int ld)
{
  __shared__ float tile[64][65];
  const int bn = blockIdx.x * 64, bk = blockIdx.y * 64;
  const int t = threadIdx.x;
  #pragma unroll
  for (int r = 0; r < 4; ++r) {
    int idx = t + 256 * r;
    int row = idx >> 4, c = (idx & 15) * 4;
    float4 v = *(const float4*)(Wsrc + (size_t)(bk + row) * ld + bn + c);
    tile[row][c] = v.x; tile[row][c+1] = v.y; tile[row][c+2] = v.z; tile[row][c+3] = v.w;
  }
  __syncthreads();
  #pragma unroll
  for (int r = 0; r < 4; ++r) {
    int idx = t + 256 * r;
    int n = bn + (idx >> 4), k = bk + (idx & 15) * 4;
    int kl = k - bk;
    float v0 = tile[kl][n - bn], v1 = tile[kl+1][n - bn], v2 = tile[kl+2][n - bn], v3 = tile[kl+3][n - bn];
    ushort4 h;
    h.x = f2bf(v0); h.y = f2bf(v1); h.z = f2bf(v2); h.w = f2bf(v3);
    size_t off = tileoff(n, k, K);
    *(ushort4*)(Th + off) = h;
    if (Tl) {
      ushort4 l;
      l.x = f2bf(v0 - bf2f(h.x)); l.y = f2bf(v1 - bf2f(h.y));
      l.z = f2bf(v2 - bf2f(h.z)); l.w = f2bf(v3 - bf2f(h.w));
      *(ushort4*)(Tl + off) = l;
    }
  }
}

// ---------------- GEMM: bf16x2 (A hi/lo x B hi), BK=64 (benched r16/r17 structure) ----------------
// A: planes Ah/Al or f32 Af (split in-flight). B: Bh only (err = a*bl ~2^-9 rel).
// epi: 0 plain, 1 C=X+acc, 2 C=silu(X)*acc, 3 QKV-fused de-concat (N=3*2048).
// split>=2: K divided into `split` chunks; chunk c writes partials to C + c*M*N.
__global__ __launch_bounds__(256) void gemm_ffn64(
    const ushort* __restrict__ Ah, const ushort* __restrict__ Al,
    const float* __restrict__ Af,
    const ushort* __restrict__ Bh,
    float* __restrict__ C, const float* __restrict__ X,
    int M, int N, int K, int epi, int split)
{
  __shared__ __align__(16) ushort sAh[8192];
  __shared__ __align__(16) ushort sAl[8192];
  __shared__ __align__(16) ushort sBh[8192];
  int flat = blockIdx.x;
  int kbeg = 0, kend = K;
  float* Cout = C;
  if (split >= 2) {
    int nb = gridDim.x / split;
    int chunk = flat / nb;
    flat -= chunk * nb;
    int kc = K / split;
    kbeg = chunk * kc; kend = kbeg + kc;
    Cout = C + (size_t)chunk * M * N;
  }
  const int MB = M >> 7;
  const int cM = MB >> 3;
  const int xcd = flat & 7, idxr = flat >> 3;
  const int byi = xcd * cM + (idxr % cM);      // A panel: XCD-resident slab
  const int bxi = idxr / cM;                   // B panel: streamed (L3)
  const int bm = byi * 128, bn = bxi * 128;
  const int t = threadIdx.x;
  const int lane = t & 63;
  const int wid = t >> 6;
  const int wr = wid >> 1, wc = wid & 1;
  const int fr = lane & 31;
  const int kg = lane >> 5;
  const int ub2 = wid * 256;                   // 1024 idx-units per 2-tile pair
  const int Ksteps = K >> 5;                   // 32-k tile units

  f32x16 acc[2][2];
  #pragma unroll
  for (int mi = 0; mi < 2; ++mi)
    #pragma unroll
    for (int ni = 0; ni < 2; ++ni)
      #pragma unroll
      for (int r = 0; r < 16; ++r) acc[mi][ni][r] = 0.f;

  for (int k0 = kbeg; k0 < kend; k0 += 64) {
    const int ks = k0 >> 5;                    // first of 2 consecutive tiles
    const size_t tB = ((size_t)(bxi * Ksteps + ks)) << 12;
    if (Af) {
      // stage A f32 128x64 -> chunk-major hi/lo images (2 tiles of 4 chunks)
      #pragma unroll
      for (int r = 0; r < 4; ++r) {
        int u = t + 256 * r;                   // 0..1023
        int row = u >> 3, ch = u & 7;          // 8 chunks of 8 cols
        const float* s0 = Af + (size_t)(bm + row) * K + k0 + ch * 8;
        float4 v0 = *(const float4*)s0, v1 = *(const float4*)(s0 + 4);
        float f[8] = {v0.x,v0.y,v0.z,v0.w,v1.x,v1.y,v1.z,v1.w};
        union { ushort u16[8]; uint4 q; } Hh, Ll;
        #pragma unroll
        for (int j = 0; j < 8; ++j) {
          ushort hh = f2bf(f[j]);
          Hh.u16[j] = hh; Ll.u16[j] = f2bf(f[j] - bf2f(hh));
        }
        int dst = (ch >> 2) * 4096 + (ch & 3) * 1024 + row * 8;
        *(uint4*)&sAh[dst] = Hh.q;
        *(uint4*)&sAl[dst] = Ll.q;
      }
    } else {
      const size_t tA = ((size_t)(byi * Ksteps + ks)) << 12;
      const ushort* a0 = Ah + tA;
      const ushort* a1 = Al + tA;
      #pragma unroll
      for (int r = 0; r < 4; ++r) {
        gload16(a0 + (size_t)(ub2 + r * 64 + lane) * 8, sAh + (ub2 + r * 64) * 8);
        gload16(a1 + (size_t)(ub2 + r * 64 + lane) * 8, sAl + (ub2 + r * 64) * 8);
      }
    }
    {
      const ushort* b0 = Bh + tB;
      #pragma unroll
      for (int r = 0; r < 4; ++r)
        gload16(b0 + (size_t)(ub2 + r * 64 + lane) * 8, sBh + (ub2 + r * 64) * 8);
    }
    __syncthreads();
    #pragma unroll
    for (int ksl = 0; ksl < 4; ++ksl) {
      const int co = (ksl >> 1) * 4096 + (((ksl & 1) * 2 + kg)) * 1024;
      bf16x8 ah[2], al[2], bh[2];
      #pragma unroll
      for (int mi = 0; mi < 2; ++mi) {
        ah[mi] = *(const bf16x8*)&sAh[co + (wr * 64 + mi * 32 + fr) * 8];
        al[mi] = *(const bf16x8*)&sAl[co + (wr * 64 + mi * 32 + fr) * 8];
        bh[mi] = *(const bf16x8*)&sBh[co + (wc * 64 + mi * 32 + fr) * 8];
      }
      __builtin_amdgcn_s_setprio(1);
      #pragma unroll
      for (int mi = 0; mi < 2; ++mi)
        #pragma unroll
        for (int ni = 0; ni < 2; ++ni) {
          acc[mi][ni] = __builtin_amdgcn_mfma_f32_32x32x16_bf16(ah[mi], bh[ni], acc[mi][ni], 0, 0, 0);
          acc[mi][ni] = __builtin_amdgcn_mfma_f32_32x32x16_bf16(al[mi], bh[ni], acc[mi][ni], 0, 0, 0);
        }
      __builtin_amdgcn_s_setprio(0);
    }
    __syncthreads();
  }
  #pragma unroll
  for (int mi = 0; mi < 2; ++mi) {
    #pragma unroll
    for (int ni = 0; ni < 2; ++ni) {
      #pragma unroll
      for (int r = 0; r < 16; ++r) {
        int row = bm + wr * 64 + mi * 32 + (r & 3) + 8 * (r >> 2) + 4 * kg;
        int col = bn + wc * 64 + ni * 32 + fr;
        float v = acc[mi][ni][r];
        size_t idx;
        if (epi == 3) {
          int mtx = col >> 11, cc = col & 2047;
          idx = ((size_t)mtx * M + row) * 2048 + cc;
        } else {
          idx = (size_t)row * N + col;
          if (split < 2) {
            if (epi == 1) v += X[idx];
            else if (epi == 2) { float g = X[idx]; v = (g / (1.f + expf(-g))) * v; }
          }
        }
        Cout[idx] = v;
      }
    }
  }
}

// ---------------- o = sum(parts[0..np)) + x (split-K reduce + residual) ----------------
__global__ __launch_bounds__(256) void reduce_n(
    const float* __restrict__ parts, const float* __restrict__ x,
    float* __restrict__ o, int np)
{
  int g = blockIdx.x * 256 + threadIdx.x;     // NQ*H/4 float4
  float4 vx = ((const float4*)x)[g];
  float4 vo = vx;
  for (int p = 0; p < np; ++p) {
    float4 vp = ((const float4*)(parts + (size_t)p * NQ_ * H_))[g];
    vo.x += vp.x; vo.y += vp.y; vo.z += vp.z; vo.w += vp.w;
  }
  ((float4*)o)[g] = vo;
}

// ---------------- RoPE in-place on q and k ----------------
__global__ __launch_bounds__(256) void rope_k(
    float* __restrict__ qb, float* __restrict__ kb, const int* __restrict__ q_pos)
{
  int gid = blockIdx.x * 256 + threadIdx.x;   // NQ*NH*64
  int d = gid & 63;
  int h = (gid >> 6) & 15;
  int i = gid >> 10;
  int p = q_pos[i];
  double ang = (double)p * exp((double)d * -0.14391156831212787);
  float c = (float)cos(ang), s = (float)sin(ang);
  size_t ia = (size_t)i * H_ + h * HD_ + d;
  size_t ib = ia + 64;
  float qa = qb[ia], qbv = qb[ib];
  qb[ia] = qa * c - qbv * s;
  qb[ib] = qbv * c + qa * s;
  float ka = kb[ia], kbv = kb[ib];
  kb[ia] = ka * c - kbv * s;
  kb[ib] = kbv * c + ka * s;
}

// ---------------- K (hi only) + V^T (hi) bf16 planes ----------------
// kh: [NH][NK][HD]; vth: TILE-MAJOR [NH][NK/64][HD][64].  grid = (NK/64, NH)
__global__ __launch_bounds__(256) void fill_kv_planes(
    const float* __restrict__ kcache, const float* __restrict__ vcache,
    const float* __restrict__ kb, const float* __restrict__ vb,
    const int* __restrict__ kv_idxs,
    ushort* __restrict__ kh, ushort* __restrict__ vth)
{
  __shared__ float vt[64][133];
  const int h = blockIdx.y;
  const int kbase = blockIdx.x * 64;
  const int t = threadIdx.x;
  #pragma unroll
  for (int r = 0; r < 8; ++r) {
    int idx = t + 256 * r;                     // 2048 float4
    int key = idx >> 5, d4 = idx & 31;
    int j = kbase + key;
    float4 kv, vv;
    if (j < NKV) {
      int tok = kv_idxs[j];
      size_t src = ((size_t)h * S_ + tok) * 32 + d4;
      kv = ((const float4*)kcache)[src];
      vv = ((const float4*)vcache)[src];
    } else {
      int i = j - NKV;
      size_t src = (size_t)i * 512 + h * 32 + d4;
      kv = ((const float4*)kb)[src];
      vv = ((const float4*)vb)[src];
    }
    ushort4 hh;
    hh.x = f2bf(kv.x); hh.y = f2bf(kv.y); hh.z = f2bf(kv.z); hh.w = f2bf(kv.w);
    size_t dst = ((size_t)(h * NK_ + j)) * 128 + d4 * 4;
    *(ushort4*)(kh + dst) = hh;
    vt[key][d4 * 4 + 0] = vv.x; vt[key][d4 * 4 + 1] = vv.y;
    vt[key][d4 * 4 + 2] = vv.z; vt[key][d4 * 4 + 3] = vv.w;
  }
  __syncthreads();
  #pragma unroll
  for (int r = 0; r < 8; ++r) {
    int idx = t + 256 * r;                     // 2048 groups of 4 keys
    int d = idx >> 4, kq = (idx & 15) * 4;
    float v0 = vt[kq + 0][d], v1 = vt[kq + 1][d], v2 = vt[kq + 2][d], v3 = vt[kq + 3][d];
    ushort4 hh;
    hh.x = f2bf(v0); hh.y = f2bf(v1); hh.z = f2bf(v2); hh.w = f2bf(v3);
    size_t dst = (((size_t)h * 64 + blockIdx.x) * 128 + d) * 64 + kq;
    *(ushort4*)(vth + dst) = hh;
  }
}

// ---------------- MFMA flash attention (4-way key-split, grid 1024, LPT order) ----------------
// (benched round-17 structure — unchanged)
struct MergeLDS4 { float buf[2][32][132]; float ml[2][2][32]; };

__global__ __launch_bounds__(256, 2) void flash_mfma(
    const float* __restrict__ qb, const ushort* __restrict__ khg,
    const ushort* __restrict__ vthg,
    const int* __restrict__ q_pos, const int* __restrict__ k_pos,
    ushort* __restrict__ ctxh, ushort* __restrict__ ctxl)
{
  __shared__ MergeLDS4 U;
  const int b = blockIdx.x;
  const int h = (b & 7) * 2 + ((b >> 3) & 1);  // 2 heads per XCD slab
  const int qb32 = 63 - (b >> 4);              // heaviest blocks first (LPT)
  const int q0 = qb32 * 32;
  const int t = threadIdx.x;
  const int wk = t >> 6, lane = t & 63;
  const int kg = lane >> 5;
  const int qc = lane & 31;
  const int qi = q0 + qc;
  const float scale = 0.08838834764831844f;    // 1/sqrt(128)

  bf16x8 qh[8], ql[8];
  {
    const float4* q4 = (const float4*)qb;
    #pragma unroll
    for (int s = 0; s < 8; ++s) {
      size_t a = (size_t)qi * 512 + h * 32 + s * 4 + kg * 2;
      float4 f0 = q4[a], f1 = q4[a + 1];
      float f[8] = {f0.x, f0.y, f0.z, f0.w, f1.x, f1.y, f1.z, f1.w};
      union { ushort u[8]; bf16x8 v; } Hq, Lq;
      #pragma unroll
      for (int j = 0; j < 8; ++j) {
        float qs = f[j] * scale;
        ushort hh = f2bf(qs);
        Hq.u[j] = hh; Lq.u[j] = f2bf(qs - bf2f(hh));
      }
      qh[s] = Hq.v; ql[s] = Lq.v;
    }
  }
  const int qp = q_pos[qi];
  const int wave_qmin = __shfl(qp, 0);
  const int wave_qmax = __shfl(qp, 31);       // q ascend within 32-block

  const ushort* kh_base = khg + (size_t)h * NK_ * 128;
  const ushort* vt_base = vthg + (size_t)h * NK_ * 128;   // [NK/64][128][64]

  f32x16 acc[4];
  #pragma unroll
  for (int f = 0; f < 4; ++f)
    #pragma unroll
    for (int r = 0; r < 16; ++r) acc[f][r] = 0.f;
  float m_run = -INFINITY, l_run = 0.f;

  for (int c = wk; c < NK_ / 32; c += 4) {     // interleaved 32-key chunks
    const int krow0 = c * 32;
    const int kpv = k_pos[krow0 + qc];
    if (__shfl(kpv, 0) > wave_qmax) continue;  // chunk fully masked
    const bool needmask = (__shfl(kpv, 31) > wave_qmin);

    f32x16 sA, sB;
    #pragma unroll
    for (int r = 0; r < 16; ++r) { sA[r] = 0.f; sB[r] = 0.f; }
    const ushort* krow = kh_base + (size_t)(krow0 + qc) * 128 + kg * 8;
    __builtin_amdgcn_s_setprio(1);
    #pragma unroll
    for (int s = 0; s < 8; ++s) {
      bf16x8 khf = *(const bf16x8*)(krow + s * 16);
      sA = __builtin_amdgcn_mfma_f32_32x32x16_bf16(khf, qh[s], sA, 0, 0, 0);
      sB = __builtin_amdgcn_mfma_f32_32x32x16_bf16(khf, ql[s], sB, 0, 0, 0);
    }
    __builtin_amdgcn_s_setprio(0);
    // V fragments from tile-major layout (issued early, hide under softmax)
    bf16x8 vf[2][4];
    {
      const ushort* vtile = vt_base + (size_t)(c >> 1) * 8192;   // 128*64
      #pragma unroll
      for (int ks = 0; ks < 2; ++ks) {
        const int kc = (c & 1) * 32 + ks * 16 + kg * 8;          // within-tile key
        #pragma unroll
        for (int f = 0; f < 4; ++f)
          vf[ks][f] = *(const bf16x8*)(vtile + (f * 32 + qc) * 64 + kc);
      }
    }
    float sc[16];
    #pragma unroll
    for (int r = 0; r < 16; ++r) sc[r] = sA[r] + sB[r];
    if (needmask) {
      #pragma unroll
      for (int r = 0; r < 16; ++r) {
        int crow = (r & 3) + 8 * (r >> 2) + 4 * kg;
        sc[r] = (__shfl(kpv, crow) <= qp) ? sc[r] : -INFINITY;
      }
    }
    float mloc = sc[0];
    #pragma unroll
    for (int r = 1; r < 16; ++r) mloc = fmaxf(mloc, sc[r]);
    mloc = fmaxf(mloc, __shfl_xor(mloc, 32));
    float m_new = fmaxf(m_run, mloc);
    float mexp = (m_new == -INFINITY) ? 0.f : m_new;
    if (__any(m_new > m_run)) {
      float aa = __expf(m_run - mexp);
      l_run *= aa;
      #pragma unroll
      for (int f = 0; f < 4; ++f)
        #pragma unroll
        for (int r = 0; r < 16; ++r) acc[f][r] *= aa;
    }
    m_run = m_new;
    float p[16]; float psum = 0.f;
    #pragma unroll
    for (int r = 0; r < 16; ++r) { p[r] = __expf(sc[r] - mexp); psum += p[r]; }
    psum += __shfl_xor(psum, 32);
    l_run += psum;
    bf16x8 pfh[2], pfl[2];
    #pragma unroll
    for (int sl = 0; sl < 2; ++sl) {
      const float* pp = p + sl * 8;
      unsigned a0 = cvt_pk_bf16(pp[0], pp[1]);
      unsigned a1 = cvt_pk_bf16(pp[2], pp[3]);
      unsigned b0 = cvt_pk_bf16(pp[4], pp[5]);
      unsigned b1 = cvt_pk_bf16(pp[6], pp[7]);
      unsigned a0x = (unsigned)__shfl_xor((int)a0, 32);
      unsigned a1x = (unsigned)__shfl_xor((int)a1, 32);
      unsigned b0x = (unsigned)__shfl_xor((int)b0, 32);
      unsigned b1x = (unsigned)__shfl_xor((int)b1, 32);
      union { unsigned wd[4]; bf16x8 v; } PH, PL;
      PH.wd[0] = kg ? b0x : a0;
      PH.wd[1] = kg ? b1x : a1;
      PH.wd[2] = kg ? b0 : a0x;
      PH.wd[3] = kg ? b1 : a1x;
      float r0 = pp[0] - bflo(a0), r1 = pp[1] - bfhi(a0);
      float r2 = pp[2] - bflo(a1), r3 = pp[3] - bfhi(a1);
      float r4 = pp[4] - bflo(b0), r5 = pp[5] - bfhi(b0);
      float r6 = pp[6] - bflo(b1), r7 = pp[7] - bfhi(b1);
      unsigned c0 = cvt_pk_bf16(r0, r1);
      unsigned c1 = cvt_pk_bf16(r2, r3);
      unsigned d0 = cvt_pk_bf16(r4, r5);
      unsigned d1 = cvt_pk_bf16(r6, r7);
      unsigned c0x = (unsigned)__shfl_xor((int)c0, 32);
      unsigned c1x = (unsigned)__shfl_xor((int)c1, 32);
      unsigned d0x = (unsigned)__shfl_xor((int)d0, 32);
      unsigned d1x = (unsigned)__shfl_xor((int)d1, 32);
      PL.wd[0] = kg ? d0x : c0;
      PL.wd[1] = kg ? d1x : c1;
      PL.wd[2] = kg ? d0 : c0x;
      PL.wd[3] = kg ? d1 : c1x;
      pfh[sl] = PH.v; pfl[sl] = PL.v;
    }
    __builtin_amdgcn_s_setprio(1);
    #pragma unroll
    for (int ks = 0; ks < 2; ++ks) {
      acc[0] = __builtin_amdgcn_mfma_f32_32x32x16_bf16(vf[ks][0], pfh[ks], acc[0], 0, 0, 0);
      acc[1] = __builtin_amdgcn_mfma_f32_32x32x16_bf16(vf[ks][1], pfh[ks], acc[1], 0, 0, 0);
      acc[2] = __builtin_amdgcn_mfma_f32_32x32x16_bf16(vf[ks][2], pfh[ks], acc[2], 0, 0, 0);
      acc[3] = __builtin_amdgcn_mfma_f32_32x32x16_bf16(vf[ks][3], pfh[ks], acc[3], 0, 0, 0);
      acc[0] = __builtin_amdgcn_mfma_f32_32x32x16_bf16(vf[ks][0], pfl[ks], acc[0], 0, 0, 0);
      acc[1] = __builtin_amdgcn_mfma_f32_32x32x16_bf16(vf[ks][1], pfl[ks], acc[1], 0, 0, 0);
      acc[2] = __builtin_amdgcn_mfma_f32_32x32x16_bf16(vf[ks][2], pfl[ks], acc[2], 0, 0, 0);
      acc[3] = __builtin_amdgcn_mfma_f32_32x32x16_bf16(vf[ks][3], pfl[ks], acc[3], 0, 0, 0);
    }
    __builtin_amdgcn_s_setprio(0);
  }

  // ---- 2-stage 4-way merge (guarded online-softmax combine) ----
  if (wk >= 2) {
    const int slot = wk - 2;
    #pragma unroll
    for (int f = 0; f < 4; ++f)
      #pragma unroll
      for (int r = 0; r < 16; ++r) {
        int d = f * 32 + (r & 3) + 8 * (r >> 2) + 4 * kg;
        U.buf[slot][qc][d] = acc[f][r];
      }
    if (kg == 0) { U.ml[slot][0][qc] = m_run; U.ml[slot][1][qc] = l_run; }
  }
  __syncthreads();
  if (wk < 2) {
    const int slot = wk;
    float m2 = U.ml[slot][0][qc];
    float l2 = U.ml[slot][1][qc];
    float mm = fmaxf(m_run, m2);
    float me = (mm == -INFINITY) ? 0.f : mm;
    float a1 = __expf(m_run - me);
    float a2 = __expf(m2 - me);
    #pragma unroll
    for (int f = 0; f < 4; ++f)
      #pragma unroll
      for (int r = 0; r < 16; ++r) {
        int d = f * 32 + (r & 3) + 8 * (r >> 2) + 4 * kg;
        acc[f][r] = acc[f][r] * a1 + U.buf[slot][qc][d] * a2;
      }
    m_run = mm; l_run = l_run * a1 + l2 * a2;
  }
  __syncthreads();
  if (wk == 1) {
    #pragma unroll
    for (int f = 0; f < 4; ++f)
      #pragma unroll
      for (int r = 0; r < 16; ++r) {
        int d = f * 32 + (r & 3) + 8 * (r >> 2) + 4 * kg;
        U.buf[0][qc][d] = acc[f][r];
      }
    if (kg == 0) { U.ml[0][0][qc] = m_run; U.ml[0][1][qc] = l_run; }
  }
  __syncthreads();
  if (wk == 0) {
    float m2 = U.ml[0][0][qc];
    float l2 = U.ml[0][1][qc];
    float mm = fmaxf(m_run, m2);
    float me = (mm == -INFINITY) ? 0.f : mm;
    float a1 = __expf(m_run - me);
    float a2 = __expf(m2 - me);
    float lt = l_run * a1 + l2 * a2;
    float inv = 1.f / lt;
    #pragma unroll
    for (int f = 0; f < 4; ++f)
      #pragma unroll
      for (int rq = 0; rq < 4; ++rq) {
        float o[4];
        #pragma unroll
        for (int j = 0; j < 4; ++j) {
          int d = f * 32 + j + 8 * rq + 4 * kg;
          o[j] = (acc[f][rq * 4 + j] * a1 + U.buf[0][qc][d] * a2) * inv;
        }
        ushort4 hh, ll;
        hh.x = f2bf(o[0]); ll.x = f2bf(o[0] - bf2f(hh.x));
        hh.y = f2bf(o[1]); ll.y = f2bf(o[1] - bf2f(hh.y));
        hh.z = f2bf(o[2]); ll.z = f2bf(o[2] - bf2f(hh.z));
        hh.w = f2bf(o[3]); ll.w = f2bf(o[3] - bf2f(hh.w));
        int d = h * 128 + f * 32 + kg * 4 + rq * 8;
        size_t oidx = tileoff(qi, d, H_);
        *(ushort4*)(ctxh + oidx) = hh;
        *(ushort4*)(ctxl + oidx) = ll;
      }
  }
}

// ---------------- cache scatter outputs ----------------
__global__ __launch_bounds__(256) void write_kv(
    const float* __restrict__ kcache, const float* __restrict__ vcache,
    const float* __restrict__ kb, const float* __restrict__ vb,
    const int* __restrict__ in_hs, const int* __restrict__ map_full,
    float* __restrict__ kc_o, float* __restrict__ vc_o)
{
  int gid = blockIdx.x * 256 + threadIdx.x;   // NH*S*HD/4
  int d4 = gid & 31;
  int s  = (gid >> 5) & (S_ - 1);
  int h  = gid >> 17;
  float4 kv, vv;
  if (in_hs[s]) {
    int i = map_full[s];
    size_t src = (size_t)i * (H_ / 4) + h * 32 + d4;
    kv = ((const float4*)kb)[src];
    vv = ((const float4*)vb)[src];
  } else {
    kv = ((const float4*)kcache)[gid];
    vv = ((const float4*)vcache)[gid];
  }
  ((float4*)kc_o)[gid] = kv;
  ((float4*)vc_o)[gid] = vv;
}

__global__ __launch_bounds__(256) void aux_write(
    const float* __restrict__ outb, const float* __restrict__ auxc,
    const int* __restrict__ pruned_bit, const int* __restrict__ aux_bit,
    const int* __restrict__ map_full, float* __restrict__ aux_o)
{
  int gid = blockIdx.x * 256 + threadIdx.x;   // S*H/4
  int c4 = gid & 511;
  int s  = gid >> 9;
  float4 v;
  if (pruned_bit[s] && !aux_bit[s])
    v = ((const float4*)outb)[(size_t)map_full[s] * 512 + c4];
  else
    v = ((const float4*)auxc)[gid];
  ((float4*)aux_o)[gid] = v;
}

// ---------------- host ----------------
extern "C" void kernel_launch(void* const* d_in, const int* in_sizes, int n_in,
                              void* d_out, int out_size, void* d_ws, size_t ws_size,
                              hipStream_t stream) {
  (void)in_sizes; (void)n_in; (void)out_size; (void)ws_size;
  const float* hidden  = (const float*)d_in[0];
  const float* kcache  = (const float*)d_in[1];
  const float* vcache  = (const float*)d_in[2];
  const float* auxc    = (const float*)d_in[3];
  const int* kv_idxs   = (const int*)d_in[4];
  const int* aux_idxs  = (const int*)d_in[5];
  const int* new_idxs  = (const int*)d_in[6];
  const int* positions = (const int*)d_in[7];
  const float* wq      = (const float*)d_in[8];
  const float* wk      = (const float*)d_in[9];
  const float* wv      = (const float*)d_in[10];
  const float* wo      = (const float*)d_in[11];
  const float* w_gate  = (const float*)d_in[12];
  const float* w_up    = (const float*)d_in[13];
  const float* w_down  = (const float*)d_in[14];
  const float* ln1     = (const float*)d_in[15];
  const float* ln2     = (const float*)d_in[16];

  float* out_o = (float*)d_out;
  float* kc_o  = out_o + (size_t)NQ_ * H_;
  float* vc_o  = kc_o + (size_t)NH_ * S_ * HD_;
  float* aux_o = vc_o + (size_t)NH_ * S_ * HD_;

  // workspace (units of M4 = 4M floats = 16.78 MB), 11 slots + ints.
  // All GEMMs now bt2/BK64 (gemm_ffn64): B-lo planes never written.
  // wo split-K=4: partials -> slots 2-5; down split-K=2: partials -> slots 0-1.
  float* W = (float*)d_ws;
  const size_t M4 = 4194304;                  // NQ*H
  float* hs    = W;
  ushort* xh   = (ushort*)(W + 1 * M4);
  ushort* xl   = xh + (size_t)NQ_ * H_;
  float* qb    = W + 2 * M4;
  float* kb    = W + 3 * M4;
  float* vb    = W + 4 * M4;
  ushort* bt3_h = (ushort*)(W + 5 * M4);      // 3*H*H ushorts (slots 5-6, QKV phase)
  ushort* khp  = (ushort*)(W + 5 * M4);
  ushort* vthp = (ushort*)(W + 7 * M4);
  ushort* ctxh = (ushort*)(W + 8 * M4);
  ushort* ctxl = ctxh + (size_t)NQ_ * H_;
  ushort* bt_h = (ushort*)(W + 9 * M4);
  float* hs2   = W + 10 * M4;
  float* act   = W + 2 * M4;                  // slots 2-5 (FFN phase)
  ushort* btg_h = (ushort*)(W + 6 * M4);      // slots 6-7
  float* wo_p  = W + 2 * M4;                  // wo split-4 partials (slots 2-5)
  float* dn_p  = W + 0 * M4;                  // down split-2 partials (slots 0-1)
  int* ip = (int*)(W + 11 * M4);
  int* hs_idxs = ip;           ip += NQ_;
  int* q_pos   = ip;           ip += NQ_;
  int* key_tok = ip;           ip += NK_;
  int* k_pos   = ip;           ip += NK_;
  int* map_full= ip;           ip += S_;
  int* in_hs   = ip;           ip += S_;
  int* aux_bit = ip;           ip += S_;
  int* pruned  = ip;           ip += S_;
  int* last_hs = ip;           ip += 4;

  prep_build<<<16, 256, 0, stream>>>(kv_idxs, aux_idxs, new_idxs, positions,
      hs_idxs, q_pos, key_tok, k_pos, map_full, in_hs, aux_bit, pruned, last_hs);
  prep_scatter<<<10, 256, 0, stream>>>(hs_idxs, aux_idxs, map_full, in_hs, aux_bit);
  prune_set<<<2, 256, 0, stream>>>(kv_idxs, pruned);
  build_hs<<<4096, 256, 0, stream>>>(hidden, auxc, aux_idxs, hs);
  rmsnorm_split<<<NQ_, 256, 0, stream>>>(hs, ln1, xh, xl);

  const dim3 gTH(H_ / 64, H_ / 64);
  // QKV fused: B = concat(wq,wk,wv) hi-panels, N = 6144, epi 3 de-concats C.
  // bt2/BK64 (err ~1.8e-3 on q/k/v — validated headroom, r17).
  wsplit_t<<<gTH, 256, 0, stream>>>(wq, bt3_h,                       nullptr, H_, H_, H_);
  wsplit_t<<<gTH, 256, 0, stream>>>(wk, bt3_h + (size_t)H_ * H_,     nullptr, H_, H_, H_);
  wsplit_t<<<gTH, 256, 0, stream>>>(wv, bt3_h + (size_t)2 * H_ * H_, nullptr, H_, H_, H_);
  gemm_ffn64<<<768, 256, 0, stream>>>(xh, xl, nullptr, bt3_h, qb, nullptr, NQ_, 3 * H_, H_, 3, 0);

  rope_k<<<8192, 256, 0, stream>>>(qb, kb, q_pos);
  fill_kv_planes<<<dim3(64, 16), 256, 0, stream>>>(kcache, vcache, kb, vb, kv_idxs,
      khp, vthp);

  flash_mfma<<<1024, 256, 0, stream>>>(qb, khp, vthp, q_pos, k_pos, ctxh, ctxl);
  write_kv<<<8192, 256, 0, stream>>>(kcache, vcache, kb, vb, in_hs, map_full, kc_o, vc_o);

  // wo GEMM: bt2/BK64, split-K=4 (grid 1024), partials in slots 2-5, residual-add
  wsplit_t<<<gTH, 256, 0, stream>>>(wo, bt_h, nullptr, H_, H_, H_);
  gemm_ffn64<<<1024, 256, 0, stream>>>(ctxh, ctxl, nullptr, bt_h, wo_p, nullptr, NQ_, H_, H_, 0, 4);
  reduce_n<<<4096, 256, 0, stream>>>(wo_p, hs, hs2, 4);
  rmsnorm_split<<<NQ_, 256, 0, stream>>>(hs2, ln2, xh, xl);

  // FFN GEMMs: bt2/BK64 (benched r16/r17)
  wsplit_t<<<dim3(FF_ / 64, H_ / 64), 256, 0, stream>>>(w_gate, btg_h, nullptr, H_, FF_, FF_);
  gemm_ffn64<<<1024, 256, 0, stream>>>(xh, xl, nullptr, btg_h, act, nullptr, NQ_, FF_, H_, 0, 0);
  wsplit_t<<<dim3(FF_ / 64, H_ / 64), 256, 0, stream>>>(w_up, btg_h, nullptr, H_, FF_, FF_);
  gemm_ffn64<<<1024, 256, 0, stream>>>(xh, xl, nullptr, btg_h, act, act, NQ_, FF_, H_, 2, 0);
  // down GEMM: split-K=2 (grid 512), f32-A split path, BK=64, partials + residual
  wsplit_t<<<dim3(H_ / 64, FF_ / 64), 256, 0, stream>>>(w_down, btg_h, nullptr, FF_, H_, H_);
  gemm_ffn64<<<512, 256, 0, stream>>>(nullptr, nullptr, act, btg_h, dn_p, nullptr, NQ_, H_, FF_, 0, 2);
  reduce_n<<<4096, 256, 0, stream>>>(dn_p, hs2, out_o, 2);

  aux_write<<<8192, 256, 0, stream>>>(out_o, auxc, pruned, aux_bit, map_full, aux_o);
}